// Round 8
// baseline (1342.497 us; speedup 1.0000x reference)
//
#include <hip/hip_runtime.h>
#include <hip/hip_cooperative_groups.h>
#include <cstddef>

namespace cg = cooperative_groups;

// Problem constants
#define B_   4
#define NS_  96
#define T_   8
#define H_   256
#define N_   97      // NS + 1
#define NL_  6       // NUM_LAYERS
#define R_   388     // B_ * N_

// fast gates: v_exp_f32 (2^x) + v_rcp_f32
__device__ __forceinline__ float sigm(float x) {
    return __builtin_amdgcn_rcpf(1.0f + __builtin_amdgcn_exp2f(-1.44269504f * x));
}
__device__ __forceinline__ float tanh_f(float x) {
    return 1.0f - 2.0f * __builtin_amdgcn_rcpf(1.0f + __builtin_amdgcn_exp2f(2.88539008f * x));
}

struct Params {
    const int* ids; const int* code_length;
    const float* embed;
    const float* Wx_s; const float* Wh_s; const float* b_s;
    const float* W_se; const float* b_se;
    const float* Wx_e; const float* Wh_e; const float* b_e;
    const float* W_sd; const float* b_sd; const float* W_d1;
    const float* init_a; const float* init_b;
    float* out;
    float* cz; float* ck; float* xz; float* hbuf; float* u; float* s;
    float* q; float* r; float* rT; float* he;
    float* spT_mid; float* spT0; float* spT5;
    float* p0; float* p1; float* c0; float* c1; float* h0; float* h1;
};

// LDS union: max member = lstm (133,632 B); 1 block/CU.
struct SH {
    union {
        struct { float Whs[256][64]; float hs[32][260]; float zp[4][32][68]; } l;
        struct { float As[32][260]; int ridx[32]; } g;
        struct { float ri[256]; float ckl[256]; float wd[256];
                 float part[8][128]; float red[128]; } s;
        struct { float qj[1024]; float wcol[128]; float red[128];
                 float parts[4][2][256]; } a;
    };
};

// One 32(M)x128(N) K=256 tile: A (or gathered embed rows) staged in LDS,
// W streamed from global (L2-hot, 16 loads in flight), micro 1x4.
__device__ void tile_gemm(SH& sh, int t, int r0, int n0,
                          const float* A, const int* ids, const float* embed,
                          const float* W, const float* bias, float* C,
                          int R, int NC, float* rT) {
    if (ids && t < 32) sh.g.ridx[t] = ids[r0 + t];
    __syncthreads();                       // also guards As reuse from prev tile
#pragma unroll
    for (int m = 0; m < 2; m++) {
        int L = m * 1024 + t;
        int r = L >> 6, c4 = (L & 63) * 4;
        int rr = r0 + r;
        float4 v = make_float4(0.f, 0.f, 0.f, 0.f);
        if (rr < R) {
            const float* ap = ids ? (embed + (size_t)sh.g.ridx[r] * 256)
                                  : (A + (size_t)rr * 256);
            v = *(const float4*)(ap + c4);
        }
        *(float4*)&sh.g.As[r][c4] = v;
    }
    __syncthreads();
    int row = t >> 5, cg = t & 31;
    float a0 = 0.f, a1 = 0.f, a2 = 0.f, a3 = 0.f;
    const float* wp = W + n0 + 4 * cg;
#pragma unroll 4
    for (int kb = 0; kb < 64; kb++) {
        float4 a4 = *(const float4*)&sh.g.As[row][4 * kb];
        float4 w0 = *(const float4*)(wp + (size_t)(4 * kb + 0) * NC);
        float4 w1 = *(const float4*)(wp + (size_t)(4 * kb + 1) * NC);
        float4 w2 = *(const float4*)(wp + (size_t)(4 * kb + 2) * NC);
        float4 w3 = *(const float4*)(wp + (size_t)(4 * kb + 3) * NC);
        a0 = fmaf(a4.x, w0.x, a0); a1 = fmaf(a4.x, w0.y, a1);
        a2 = fmaf(a4.x, w0.z, a2); a3 = fmaf(a4.x, w0.w, a3);
        a0 = fmaf(a4.y, w1.x, a0); a1 = fmaf(a4.y, w1.y, a1);
        a2 = fmaf(a4.y, w1.z, a2); a3 = fmaf(a4.y, w1.w, a3);
        a0 = fmaf(a4.z, w2.x, a0); a1 = fmaf(a4.z, w2.y, a1);
        a2 = fmaf(a4.z, w2.z, a2); a3 = fmaf(a4.z, w2.w, a3);
        a0 = fmaf(a4.w, w3.x, a0); a1 = fmaf(a4.w, w3.y, a1);
        a2 = fmaf(a4.w, w3.z, a2); a3 = fmaf(a4.w, w3.w, a3);
    }
    int rg = r0 + row;
    if (rg < R) {
        int col = n0 + 4 * cg;
        float4 o = make_float4(a0, a1, a2, a3);
        if (bias) {
            float4 bv = *(const float4*)&bias[col];
            o.x += bv.x; o.y += bv.y; o.z += bv.z; o.w += bv.w;
        }
        *(float4*)&C[(size_t)rg * NC + col] = o;
        if (rT) {
            int b = rg / N_, n = rg - b * N_;
            rT[((size_t)b * 256 + col + 0) * 128 + n] = o.x;
            rT[((size_t)b * 256 + col + 1) * 128 + n] = o.y;
            rT[((size_t)b * 256 + col + 2) * 128 + n] = o.z;
            rT[((size_t)b * 256 + col + 3) * 128 + n] = o.w;
        }
    }
}

__device__ void agg_phase(SH& sh, const Params& P, int bid, int t,
                          const float* spT, const float* pc,
                          const float* cc, const float* hc,
                          float* cn, float* hn, float* pn) {
    for (int bj = bid; bj < R_; bj += 256) {
        int b = bj / N_, j = bj - b * N_;
        __syncthreads();
        if (t < 128) sh.a.wcol[t] = (t < N_) ? spT[(size_t)bj * 128 + t] * pc[b * N_ + t] : 0.f;
        __syncthreads();
        if (t < 128) sh.a.red[t] = sh.a.wcol[t];
        __syncthreads();
        for (int off = 64; off; off >>= 1) {
            if (t < off) sh.a.red[t] += sh.a.red[t + off];
            __syncthreads();
        }
        float wsum = sh.a.red[0];
        if (wsum == 0.f) {               // no mass reaches j: exact zeros
            if (t < 256) {
                cn[(size_t)bj * 256 + t] = 0.f;
                hn[(size_t)bj * 256 + t] = 0.f;
            }
            if (t == 0) pn[bj] = 0.f;
            continue;
        }
        sh.a.qj[t] = P.q[(size_t)bj * 1024 + t];
        __syncthreads();
        int hh = t & 255, vs = t >> 8;
        float ac = 0.f, ah = 0.f;
        for (int i = vs; i < N_; i += 4) {
            float wv = sh.a.wcol[i];
            if (wv == 0.f) continue;     // wave-uniform branch
            size_t rowi = (size_t)b * N_ + i;
            if (j > i) {
                const float* qi = P.q + rowi * 1024;
                const float* hei = P.he + rowi * 1024;
                float gi = sh.a.qj[hh] - qi[hh] + hei[hh];
                float gf = sh.a.qj[256 + hh] - qi[256 + hh] + hei[256 + hh];
                float gg = sh.a.qj[512 + hh] - qi[512 + hh] + hei[512 + hh];
                float go = sh.a.qj[768 + hh] - qi[768 + hh] + hei[768 + hh];
                float c2 = cc[rowi * 256 + hh];
                float cp = sigm(gf) * c2 + sigm(gi) * tanh_f(gg);
                float hp = sigm(go) * tanh_f(cp);
                ac = fmaf(wv, cp, ac);
                ah = fmaf(wv, hp, ah);
            } else {
                ac = fmaf(wv, cc[rowi * 256 + hh], ac);
                ah = fmaf(wv, hc[rowi * 256 + hh], ah);
            }
        }
        sh.a.parts[vs][0][hh] = ac;
        sh.a.parts[vs][1][hh] = ah;
        __syncthreads();
        if (t < 256) {
            float inv = __builtin_amdgcn_rcpf(wsum + 1e-7f);
            float cs = sh.a.parts[0][0][hh] + sh.a.parts[1][0][hh]
                     + sh.a.parts[2][0][hh] + sh.a.parts[3][0][hh];
            float hs2 = sh.a.parts[0][1][hh] + sh.a.parts[1][1][hh]
                      + sh.a.parts[2][1][hh] + sh.a.parts[3][1][hh];
            cn[(size_t)bj * 256 + hh] = cs * inv;
            hn[(size_t)bj * 256 + hh] = hs2 * inv;
            if (t == 0) pn[bj] = wsum;
        }
    }
}

__global__ __launch_bounds__(1024) void mega(Params P) {
    __shared__ SH sh;
    cg::grid_group grid = cg::this_grid();
    int bid = blockIdx.x;
    int t = threadIdx.x;

    // ================= P0: xz GEMM + bias preps + state init =================
    for (int task = bid; task < 867; task += 256) {
        if (task < 768) {                 // xz = embed[ids] @ Wx_s + b_s
            int r0 = (task >> 3) * 32, n0 = (task & 7) * 128;
            tile_gemm(sh, t, r0, n0, nullptr, P.ids, P.embed, P.Wx_s, P.b_s,
                      P.xz, 3072, 1024, nullptr);
        } else if (task < 770) {          // cz / ck
            int idx = (task - 768) * 1024 + t;
            if (idx < 1024) {
                float acc = P.b_e[idx];
                for (int k = 0; k < 256; k++)
                    acc = fmaf(P.b_se[k], P.Wx_e[(size_t)k * 1024 + idx], acc);
                P.cz[idx] = acc;
            } else if (idx < 1280) {
                int m2 = idx - 1024;
                float acc = P.b_sd[m2];
                for (int k = 0; k < 256; k++)
                    acc = fmaf(P.b_se[k], P.W_sd[(size_t)k * 256 + m2], acc);
                P.ck[m2] = acc;
            }
        } else {                          // init c0/h0/p0
            int idx = (task - 770) * 1024 + t;
            if (idx < R_ * 256) {
                int row = idx >> 8, col = idx & 255;
                P.c0[idx] = P.init_a[col];
                P.h0[idx] = P.init_b[col];
                if (col == 0) P.p0[row] = ((row % N_) == 0) ? 1.0f : 0.0f;
            }
        }
    }
    grid.sync();                                           // S1

    // ================= LSTM: Wh slice persistent in LDS =================
    bool lact = bid < 192;
    int ct = bid & 15, st = bid >> 4;     // 16 col-tiles x 12 stripes
    int et0 = ct * 16, s0 = st * 32;
    float creg = 0.f;
    if (lact) {
#pragma unroll
        for (int m = 0; m < 4; m++) {     // stage Wh slice once (64 KB)
            int L = m * 1024 + t;
            int k = L >> 4, f4 = L & 15;
            int gg = f4 >> 2, qq = f4 & 3;
            *(float4*)&sh.l.Whs[k][f4 * 4] =
                *(const float4*)&P.Wh_s[(size_t)k * 1024 + gg * 256 + et0 + qq * 4];
        }
        {   // bootstrap h0 into hs (all 256 cols of stripe) from xz step 0
            int seq = t >> 5, e8 = (t & 31) * 8;
            const float* z0 = P.xz + ((size_t)(s0 + seq) * T_) * 1024;
#pragma unroll
            for (int u = 0; u < 8; u++) {
                int e = e8 + u;
                float gi = z0[e], gf = z0[256 + e], gg2 = z0[512 + e], go = z0[768 + e];
                (void)gf;
                float cn0 = sigm(gi) * tanh_f(gg2);
                sh.l.hs[seq][e] = sigm(go) * tanh_f(cn0);
            }
        }
        if (t < 512) {                    // own cell's c0
            int sq = t >> 4, e = et0 + (t & 15);
            const float* z0 = P.xz + ((size_t)(s0 + sq) * T_) * 1024;
            float gi = z0[e], gg2 = z0[512 + e];
            creg = sigm(gi) * tanh_f(gg2);
        }
    }
    __syncthreads();
    for (int step = 1; step < 8; step++) {
        if (lact) {
            int kg = t >> 8, sp = (t >> 4) & 15, cq = t & 15;
            int g = cq >> 2, q4v = cq & 3;
            int gcol = g * 256 + et0 + q4v * 4;
            float4 acc0, acc1;
            if (kg == 0) {
                acc0 = *(const float4*)(P.xz + ((size_t)(s0 + sp) * T_ + step) * 1024 + gcol);
                acc1 = *(const float4*)(P.xz + ((size_t)(s0 + sp + 16) * T_ + step) * 1024 + gcol);
            } else {
                acc0 = make_float4(0.f, 0.f, 0.f, 0.f);
                acc1 = make_float4(0.f, 0.f, 0.f, 0.f);
            }
            int k0 = kg * 64;
#pragma unroll 4
            for (int k = 0; k < 64; k++) {
                float4 w4 = *(const float4*)&sh.l.Whs[k0 + k][cq * 4];
                float hA = sh.l.hs[sp][k0 + k];
                float hB = sh.l.hs[sp + 16][k0 + k];
                acc0.x = fmaf(hA, w4.x, acc0.x); acc0.y = fmaf(hA, w4.y, acc0.y);
                acc0.z = fmaf(hA, w4.z, acc0.z); acc0.w = fmaf(hA, w4.w, acc0.w);
                acc1.x = fmaf(hB, w4.x, acc1.x); acc1.y = fmaf(hB, w4.y, acc1.y);
                acc1.z = fmaf(hB, w4.z, acc1.z); acc1.w = fmaf(hB, w4.w, acc1.w);
            }
            *(float4*)&sh.l.zp[kg][sp][cq * 4] = acc0;
            *(float4*)&sh.l.zp[kg][sp + 16][cq * 4] = acc1;
        }
        __syncthreads();
        if (lact && t < 512) {
            int sq = t >> 4, e = t & 15;
            float gi = sh.l.zp[0][sq][e]      + sh.l.zp[1][sq][e]      + sh.l.zp[2][sq][e]      + sh.l.zp[3][sq][e];
            float gf = sh.l.zp[0][sq][16 + e] + sh.l.zp[1][sq][16 + e] + sh.l.zp[2][sq][16 + e] + sh.l.zp[3][sq][16 + e];
            float gg = sh.l.zp[0][sq][32 + e] + sh.l.zp[1][sq][32 + e] + sh.l.zp[2][sq][32 + e] + sh.l.zp[3][sq][32 + e];
            float go = sh.l.zp[0][sq][48 + e] + sh.l.zp[1][sq][48 + e] + sh.l.zp[2][sq][48 + e] + sh.l.zp[3][sq][48 + e];
            float cn2 = sigm(gf) * creg + sigm(gi) * tanh_f(gg);
            creg = cn2;
            P.hbuf[(size_t)(s0 + sq) * 256 + et0 + e] = sigm(go) * tanh_f(cn2);
        }
        grid.sync();                                       // S2..S8
        if (step < 7) {
            if (lact) {
#pragma unroll
                for (int m = 0; m < 2; m++) {
                    int L = m * 1024 + t;
                    int seq = L >> 6, c4 = (L & 63) * 4;
                    *(float4*)&sh.l.hs[seq][c4] =
                        *(const float4*)&P.hbuf[(size_t)(s0 + seq) * 256 + c4];
                }
            }
            __syncthreads();
        }
    }

    // ================= u = stmt @ W_se =================
    if (bid < 24) {
        int r0 = (bid >> 1) * 32, n0 = (bid & 1) * 128;
        tile_gemm(sh, t, r0, n0, P.hbuf, nullptr, nullptr, P.W_se, nullptr,
                  P.u, 384, 256, nullptr);
    }
    grid.sync();                                           // S9

    // ================= cumsum -> s =================
    if (bid < 4 && t < 256) {
        float run = 0.f;
        P.s[((size_t)bid * N_) * 256 + t] = 0.f;
        for (int n = 1; n < N_; n++) {
            run += P.u[((size_t)(bid * NS_ + n - 1)) * 256 + t];
            P.s[((size_t)(bid * N_ + n)) * 256 + t] = run;
        }
    }
    grid.sync();                                           // S10

    // ================= q, r(+rT), he0 in one phase =================
    if (bid < 234) {
        if (bid < 104) {
            int r0 = (bid >> 3) * 32, n0 = (bid & 7) * 128;
            tile_gemm(sh, t, r0, n0, P.s, nullptr, nullptr, P.Wx_e, nullptr,
                      P.q, R_, 1024, nullptr);
        } else if (bid < 130) {
            int i2 = bid - 104;
            int r0 = (i2 >> 1) * 32, n0 = (i2 & 1) * 128;
            tile_gemm(sh, t, r0, n0, P.s, nullptr, nullptr, P.W_sd, nullptr,
                      P.r, R_, 256, P.rT);
        } else {
            int i3 = bid - 130;
            int r0 = (i3 >> 3) * 32, n0 = (i3 & 7) * 128;
            tile_gemm(sh, t, r0, n0, P.h0, nullptr, nullptr, P.Wh_e, P.cz,
                      P.he, R_, 1024, nullptr);
        }
    }
    grid.sync();                                           // S11

    // ================= softmax (layer-invariant) =================
    for (int bi = bid; bi < R_; bi += 256) {
        int b = bi / N_, i = bi - b * N_;
        __syncthreads();
        if (t < 256) {
            sh.s.ri[t] = P.r[(size_t)bi * 256 + t];
            sh.s.ckl[t] = P.ck[t];
            sh.s.wd[t] = P.W_d1[256 + t];
        }
        __syncthreads();
        int len = P.code_length[b] / T_;
        int j = t & 127, half = t >> 7;
        bool valid = (j < N_) && ((j > i && j <= len) || (j == len));
        float acc = 0.f;
        if (valid) {
            const float* rTb = P.rT + (size_t)b * 256 * 128 + j;
            int h0v = half * 32;
#pragma unroll 4
            for (int hh = 0; hh < 32; hh++) {
                int h = h0v + hh;
                float v = rTb[(size_t)h * 128] - sh.s.ri[h] + sh.s.ckl[h];
                acc = fmaf(fmaxf(v, 0.f), sh.s.wd[h], acc);
            }
        }
        sh.s.part[half][j] = acc;
        __syncthreads();
        float logit = -3.0e38f;
        if (t < 128) {
            if (valid)
                logit = sh.s.part[0][j] + sh.s.part[1][j] + sh.s.part[2][j] + sh.s.part[3][j]
                      + sh.s.part[4][j] + sh.s.part[5][j] + sh.s.part[6][j] + sh.s.part[7][j];
            sh.s.red[j] = logit;
        }
        __syncthreads();
        for (int off = 64; off; off >>= 1) {
            if (t < off) sh.s.red[t] = fmaxf(sh.s.red[t], sh.s.red[t + off]);
            __syncthreads();
        }
        float mx = sh.s.red[0];
        __syncthreads();
        float e = (t < 128 && valid) ? __builtin_amdgcn_exp2f(1.44269504f * (logit - mx)) : 0.f;
        if (t < 128) sh.s.red[j] = e;
        __syncthreads();
        for (int off = 64; off; off >>= 1) {
            if (t < off) sh.s.red[t] += sh.s.red[t + off];
            __syncthreads();
        }
        float ssum = sh.s.red[0];
        if (t < 128 && j < N_) {
            size_t o = ((size_t)b * N_ + j) * 128 + i;
            P.spT_mid[o] = e / ssum;
            P.spT0[o] = (j == 1) ? 1.f : 0.f;
            P.spT5[o] = (j == len) ? 1.f : 0.f;
        }
    }
    grid.sync();                                           // S12

    // ================= 6 execution layers =================
    for (int l = 0; l < NL_; l++) {
        bool odd = l & 1;
        const float* pc = odd ? P.p1 : P.p0;
        float* pn = odd ? P.p0 : P.p1;
        const float* cc = odd ? P.c1 : P.c0;
        float* cn = odd ? P.c0 : P.c1;
        const float* hc = odd ? P.h1 : P.h0;
        float* hn = odd ? P.h0 : P.h1;
        if (l == NL_ - 1) hn = P.out;
        const float* spT = (l == 0) ? P.spT0 : (l == NL_ - 1) ? P.spT5 : P.spT_mid;
        agg_phase(sh, P, bid, t, spT, pc, cc, hc, cn, hn, pn);
        grid.sync();
        if (l < NL_ - 1) {
            if (bid < 104) {
                int r0 = (bid >> 3) * 32, n0 = (bid & 7) * 128;
                tile_gemm(sh, t, r0, n0, hn, nullptr, nullptr, P.Wh_e, P.cz,
                          P.he, R_, 1024, nullptr);
            }
            grid.sync();
        }
    }
}

// ---------------- host launcher ----------------

extern "C" void kernel_launch(void* const* d_in, const int* in_sizes, int n_in,
                              void* d_out, int out_size, void* d_ws, size_t ws_size,
                              hipStream_t stream) {
    Params P;
    P.ids = (const int*)d_in[0];
    P.code_length = (const int*)d_in[1];
    P.embed = (const float*)d_in[2];
    P.Wx_s = (const float*)d_in[3];
    P.Wh_s = (const float*)d_in[4];
    P.b_s  = (const float*)d_in[5];
    P.W_se = (const float*)d_in[6];
    P.b_se = (const float*)d_in[7];
    P.Wx_e = (const float*)d_in[8];
    P.Wh_e = (const float*)d_in[9];
    P.b_e  = (const float*)d_in[10];
    P.W_sd = (const float*)d_in[13];
    P.b_sd = (const float*)d_in[14];
    P.W_d1 = (const float*)d_in[15];
    // d_in[11] W_hk, d_in[12] b_hk, d_in[16] b_d1: softmax-invariant -> unused
    P.init_a = (const float*)d_in[17];
    P.init_b = (const float*)d_in[18];
    P.out = (float*)d_out;

    float* wsf = (float*)d_ws;
    size_t off = 0;
    auto alloc = [&](size_t n) { float* p = wsf + off; off += n; return p; };
    P.cz = alloc(1024);
    P.ck = alloc(256);
    P.xz = alloc((size_t)3072 * 1024);
    P.hbuf = alloc(384 * 256);
    P.u = alloc(384 * 256);
    P.s = alloc(R_ * 256);
    P.q = alloc(R_ * 1024);
    P.r = alloc(R_ * 256);
    P.rT = alloc(4 * 256 * 128);
    P.he = alloc(R_ * 1024);
    P.spT_mid = alloc(R_ * 128);
    P.spT0 = alloc(R_ * 128);
    P.spT5 = alloc(R_ * 128);
    P.p0 = alloc(R_);
    P.p1 = alloc(R_);
    P.c0 = alloc(R_ * 256);
    P.c1 = alloc(R_ * 256);
    P.h0 = alloc(R_ * 256);
    P.h1 = alloc(R_ * 256);

    void* args[] = { (void*)&P };
    hipLaunchCooperativeKernel((void*)mega, dim3(256), dim3(1024), args, 0, stream);
}

// Round 9
// 455.929 us; speedup vs baseline: 2.9445x; 2.9445x over previous
//
#include <hip/hip_runtime.h>
#include <cstddef>

// Problem constants
#define B_   4
#define NS_  96
#define T_   8
#define H_   256
#define N_   97      // NS + 1
#define NL_  6       // NUM_LAYERS
#define R_   388     // B_ * N_

// fast gates: v_exp_f32 (2^x) + v_rcp_f32
__device__ __forceinline__ float sigm(float x) {
    return __builtin_amdgcn_rcpf(1.0f + __builtin_amdgcn_exp2f(-1.44269504f * x));
}
__device__ __forceinline__ float tanh_f(float x) {
    return 1.0f - 2.0f * __builtin_amdgcn_rcpf(1.0f + __builtin_amdgcn_exp2f(2.88539008f * x));
}

// ============ templated GEMM: C[R,NC] = A[R,256] @ W[256,NC] (+bias) (-subQ) ============
// MT x 128 tile, 256 thr, (MT/8) x 4 micro. A (or gathered embed rows) in LDS;
// W streamed from global (L2-hot, 4 independent b128 in flight per kb).
template<int MT>
__global__ __launch_bounds__(256) void gemm_t(const float* __restrict__ A,
        const int* __restrict__ ids, const float* __restrict__ embed,
        const float* __restrict__ W, const float* __restrict__ bias,
        const float* __restrict__ subQ, float* __restrict__ C, int R, int NC) {
    __shared__ float As[MT][260];
    __shared__ int ridx[MT];
    int t = threadIdx.x;
    int n0 = blockIdx.x * 128;
    int r0 = blockIdx.y * MT;
    if (ids) {
        if (t < MT) ridx[t] = (r0 + t < R) ? ids[r0 + t] : 0;
        __syncthreads();
    }
#pragma unroll
    for (int m = 0; m < MT / 4; m++) {
        int L = m * 256 + t;
        int r = L >> 6, c4 = (L & 63) * 4;
        int rr = r0 + r;
        float4 v = make_float4(0.f, 0.f, 0.f, 0.f);
        if (rr < R) {
            const float* ap = ids ? (embed + (size_t)ridx[r] * 256)
                                  : (A + (size_t)rr * 256);
            v = *(const float4*)(ap + c4);
        }
        *(float4*)&As[r][c4] = v;
    }
    __syncthreads();
    constexpr int RT = MT / 8;
    int rg = t >> 5, cg = t & 31;
    float acc[RT][4] = {};
    const float* wp = W + n0 + 4 * cg;
#pragma unroll 2
    for (int kb = 0; kb < 64; kb++) {
        float4 w0 = *(const float4*)(wp + (size_t)(4 * kb + 0) * NC);
        float4 w1 = *(const float4*)(wp + (size_t)(4 * kb + 1) * NC);
        float4 w2 = *(const float4*)(wp + (size_t)(4 * kb + 2) * NC);
        float4 w3 = *(const float4*)(wp + (size_t)(4 * kb + 3) * NC);
#pragma unroll
        for (int i = 0; i < RT; i++) {
            float4 a = *(const float4*)&As[rg * RT + i][4 * kb];
            acc[i][0] = fmaf(a.x, w0.x, acc[i][0]);
            acc[i][1] = fmaf(a.x, w0.y, acc[i][1]);
            acc[i][2] = fmaf(a.x, w0.z, acc[i][2]);
            acc[i][3] = fmaf(a.x, w0.w, acc[i][3]);
            acc[i][0] = fmaf(a.y, w1.x, acc[i][0]);
            acc[i][1] = fmaf(a.y, w1.y, acc[i][1]);
            acc[i][2] = fmaf(a.y, w1.z, acc[i][2]);
            acc[i][3] = fmaf(a.y, w1.w, acc[i][3]);
            acc[i][0] = fmaf(a.z, w2.x, acc[i][0]);
            acc[i][1] = fmaf(a.z, w2.y, acc[i][1]);
            acc[i][2] = fmaf(a.z, w2.z, acc[i][2]);
            acc[i][3] = fmaf(a.z, w2.w, acc[i][3]);
            acc[i][0] = fmaf(a.w, w3.x, acc[i][0]);
            acc[i][1] = fmaf(a.w, w3.y, acc[i][1]);
            acc[i][2] = fmaf(a.w, w3.z, acc[i][2]);
            acc[i][3] = fmaf(a.w, w3.w, acc[i][3]);
        }
    }
    int col = n0 + 4 * cg;
    float4 bv = make_float4(0.f, 0.f, 0.f, 0.f);
    if (bias) bv = *(const float4*)&bias[col];
#pragma unroll
    for (int i = 0; i < RT; i++) {
        int r = r0 + rg * RT + i;
        if (r < R) {
            float4 o = make_float4(acc[i][0] + bv.x, acc[i][1] + bv.y,
                                   acc[i][2] + bv.z, acc[i][3] + bv.w);
            if (subQ) {
                float4 s4 = *(const float4*)(subQ + (size_t)r * NC + col);
                o.x -= s4.x; o.y -= s4.y; o.z -= s4.z; o.w -= s4.w;
            }
            *(float4*)&C[(size_t)r * NC + col] = o;
        }
    }
}

// ============ merged q/r GEMM: blockIdx.x<8 -> q = s@Wx_e ; else r = s@W_sd (+rT) ============
__global__ __launch_bounds__(256) void qr_kernel(const float* __restrict__ S,
        const float* __restrict__ Wx_e, const float* __restrict__ W_sd,
        float* __restrict__ q, float* __restrict__ r_, float* __restrict__ rT) {
    __shared__ float As[16][260];
    int t = threadIdx.x;
    int bx = blockIdx.x;
    int r0 = blockIdx.y * 16;
#pragma unroll
    for (int m = 0; m < 4; m++) {
        int L = m * 256 + t;
        int r = L >> 6, c4 = (L & 63) * 4;
        int rr = r0 + r;
        float4 v = make_float4(0.f, 0.f, 0.f, 0.f);
        if (rr < R_) v = *(const float4*)(S + (size_t)rr * 256 + c4);
        *(float4*)&As[r][c4] = v;
    }
    __syncthreads();
    bool isq = bx < 8;
    const float* W = isq ? Wx_e : W_sd;
    int NC = isq ? 1024 : 256;
    int n0 = (isq ? bx : bx - 8) * 128;
    float* C = isq ? q : r_;
    int rg = t >> 5, cg = t & 31;
    float acc[2][4] = {};
    const float* wp = W + n0 + 4 * cg;
#pragma unroll 2
    for (int kb = 0; kb < 64; kb++) {
        float4 w0 = *(const float4*)(wp + (size_t)(4 * kb + 0) * NC);
        float4 w1 = *(const float4*)(wp + (size_t)(4 * kb + 1) * NC);
        float4 w2 = *(const float4*)(wp + (size_t)(4 * kb + 2) * NC);
        float4 w3 = *(const float4*)(wp + (size_t)(4 * kb + 3) * NC);
#pragma unroll
        for (int i = 0; i < 2; i++) {
            float4 a = *(const float4*)&As[rg * 2 + i][4 * kb];
            acc[i][0] = fmaf(a.x, w0.x, acc[i][0]);
            acc[i][1] = fmaf(a.x, w0.y, acc[i][1]);
            acc[i][2] = fmaf(a.x, w0.z, acc[i][2]);
            acc[i][3] = fmaf(a.x, w0.w, acc[i][3]);
            acc[i][0] = fmaf(a.y, w1.x, acc[i][0]);
            acc[i][1] = fmaf(a.y, w1.y, acc[i][1]);
            acc[i][2] = fmaf(a.y, w1.z, acc[i][2]);
            acc[i][3] = fmaf(a.y, w1.w, acc[i][3]);
            acc[i][0] = fmaf(a.z, w2.x, acc[i][0]);
            acc[i][1] = fmaf(a.z, w2.y, acc[i][1]);
            acc[i][2] = fmaf(a.z, w2.z, acc[i][2]);
            acc[i][3] = fmaf(a.z, w2.w, acc[i][3]);
            acc[i][0] = fmaf(a.w, w3.x, acc[i][0]);
            acc[i][1] = fmaf(a.w, w3.y, acc[i][1]);
            acc[i][2] = fmaf(a.w, w3.z, acc[i][2]);
            acc[i][3] = fmaf(a.w, w3.w, acc[i][3]);
        }
    }
    int col = n0 + 4 * cg;
#pragma unroll
    for (int i = 0; i < 2; i++) {
        int r = r0 + rg * 2 + i;
        if (r < R_) {
            float4 o = make_float4(acc[i][0], acc[i][1], acc[i][2], acc[i][3]);
            *(float4*)&C[(size_t)r * NC + col] = o;
            if (!isq) {
                int b = r / N_, n = r - b * N_;
                rT[((size_t)b * 256 + col + 0) * 128 + n] = o.x;
                rT[((size_t)b * 256 + col + 1) * 128 + n] = o.y;
                rT[((size_t)b * 256 + col + 2) * 128 + n] = o.z;
                rT[((size_t)b * 256 + col + 3) * 128 + n] = o.w;
            }
        }
    }
}

// ============ tiny bias prep: cz = b_se@Wx_e + b_e ; ck = b_se@W_sd + b_sd ============
__global__ void bias_prep(const float* __restrict__ b_se, const float* __restrict__ Wx_e,
                          const float* __restrict__ b_e, const float* __restrict__ W_sd,
                          const float* __restrict__ b_sd, float* __restrict__ cz,
                          float* __restrict__ ck) {
    __shared__ float a[256];
    int t = threadIdx.x;
    int n = blockIdx.x * 256 + t;    // 0..1279
    a[t] = b_se[t];
    __syncthreads();
    if (n < 1024) {
        float acc = b_e[n];
        for (int k = 0; k < 256; k++) acc = fmaf(a[k], Wx_e[k * 1024 + n], acc);
        cz[n] = acc;
    } else {
        int m = n - 1024;
        float acc = b_sd[m];
        for (int k = 0; k < 256; k++) acc = fmaf(a[k], W_sd[k * 256 + m], acc);
        ck[m] = acc;
    }
}

// ============ LSTM one step: 12 stripes x 16 col-tiles, Wh slice + h stripe in LDS ============
__global__ void lstm_step(int step, const float* __restrict__ xz, const float* __restrict__ Wh,
                          float* __restrict__ hbuf, float* __restrict__ cbuf) {
    __shared__ float Wh_s[256][64];  // 64 KB
    __shared__ float h_s[32][260];
    __shared__ float zs[32][68];
    int t = threadIdx.x;             // 0..255
    int ct = blockIdx.x;             // col tile 0..15
    int st = blockIdx.y;             // stripe 0..11
    int et0 = ct * 16;
    int s0 = st * 32;
    int sp = t >> 4;
    int cq = t & 15;
    int g = cq >> 2, q4 = cq & 3;
    int gcol = g * 256 + et0 + q4 * 4;

    float4 a0, a1;
    {
        const float* x0 = xz + (((size_t)(s0 + sp)) * T_ + step) * 1024 + gcol;
        const float* x1 = xz + (((size_t)(s0 + sp + 16)) * T_ + step) * 1024 + gcol;
        a0 = *(const float4*)x0;
        a1 = *(const float4*)x1;
    }
    if (step > 0) {
#pragma unroll
        for (int m = 0; m < 16; m++) {
            int L = m * 256 + t;
            int k = L >> 4, f = L & 15;
            int gg = f >> 2, qq = f & 3;
            *(float4*)&Wh_s[k][f * 4] = *(const float4*)&Wh[(size_t)k * 1024 + gg * 256 + et0 + qq * 4];
        }
#pragma unroll
        for (int m = 0; m < 8; m++) {
            int L = m * 256 + t;
            int seq = L >> 6, c4 = (L & 63) * 4;
            *(float4*)&h_s[seq][c4] = *(const float4*)&hbuf[(size_t)(s0 + seq) * H_ + c4];
        }
        __syncthreads();
#pragma unroll 4
        for (int k = 0; k < 256; k++) {
            float4 w4 = *(const float4*)&Wh_s[k][cq * 4];
            float h0 = h_s[sp][k];
            float h1 = h_s[sp + 16][k];
            a0.x = fmaf(h0, w4.x, a0.x);
            a0.y = fmaf(h0, w4.y, a0.y);
            a0.z = fmaf(h0, w4.z, a0.z);
            a0.w = fmaf(h0, w4.w, a0.w);
            a1.x = fmaf(h1, w4.x, a1.x);
            a1.y = fmaf(h1, w4.y, a1.y);
            a1.z = fmaf(h1, w4.z, a1.z);
            a1.w = fmaf(h1, w4.w, a1.w);
        }
    }
    *(float4*)&zs[sp][cq * 4] = a0;
    *(float4*)&zs[sp + 16][cq * 4] = a1;
    __syncthreads();
    int seqA = t >> 4, e = t & 15;
#pragma unroll
    for (int u = 0; u < 2; u++) {
        int seq = seqA + u * 16;
        float gi = zs[seq][0 * 16 + e];
        float gf = zs[seq][1 * 16 + e];
        float gg = zs[seq][2 * 16 + e];
        float go = zs[seq][3 * 16 + e];
        size_t gidx = (size_t)(s0 + seq) * H_ + et0 + e;
        float cprev = (step > 0) ? cbuf[gidx] : 0.0f;
        float cnew = sigm(gf) * cprev + sigm(gi) * tanh_f(gg);
        cbuf[gidx] = cnew;
        hbuf[gidx] = sigm(go) * tanh_f(cnew);
    }
}

// ============ prefix sums over statements ============
__global__ void cumsum_k(const float* __restrict__ stmt, float* __restrict__ pref) {
    int b = blockIdx.x, t = threadIdx.x;
    float run = 0.0f;
    pref[((size_t)b * N_) * H_ + t] = 0.0f;
    for (int n = 1; n < N_; n++) {
        run += stmt[((size_t)b * NS_ + n - 1) * H_ + t];
        pref[((size_t)b * N_ + n) * H_ + t] = run;
    }
}

// ============ init c/h/p ============
__global__ void init_state(const float* __restrict__ ia, const float* __restrict__ ib,
                           float* __restrict__ c0, float* __restrict__ h0,
                           float* __restrict__ p0) {
    int row = blockIdx.x, t = threadIdx.x;
    size_t idx = (size_t)row * H_ + t;
    c0[idx] = ia[t];
    h0[idx] = ib[t];
    if (t == 0) p0[row] = ((row % N_) == 0) ? 1.0f : 0.0f;
}

// ============ ONCE: logits + masked softmax (layer-invariant) ============
__global__ void softmax_once(const float* __restrict__ r, const float* __restrict__ rT,
                             const float* __restrict__ ck, const float* __restrict__ Wd1,
                             const int* __restrict__ code_length,
                             float* __restrict__ spT_mid, float* __restrict__ spT0,
                             float* __restrict__ spT5) {
    __shared__ float ri[H_], ckl[H_], wd[H_];
    __shared__ float part[8][128];
    __shared__ float red[128];
    int t = threadIdx.x;             // 0..1023
    int j = t & 127, half = t >> 7;
    int bi = blockIdx.x;
    int b = bi / N_, i = bi % N_;
    if (t < H_) {
        ri[t] = r[(size_t)bi * H_ + t];
        ckl[t] = ck[t];
        wd[t] = Wd1[256 + t];
    }
    __syncthreads();
    int len = code_length[b] / T_;
    bool valid = (j < N_) && ((j > i && j <= len) || (j == len));
    float acc = 0.0f;
    if (valid) {
        const float* rTb = rT + (size_t)b * H_ * 128 + j;
        int h0 = half * 32;
#pragma unroll 4
        for (int hh = 0; hh < 32; hh++) {
            int h = h0 + hh;
            float v = rTb[(size_t)h * 128] - ri[h] + ckl[h];
            acc = fmaf(fmaxf(v, 0.0f), wd[h], acc);
        }
    }
    part[half][j] = acc;
    __syncthreads();
    float logit = -3.0e38f;
    if (t < 128) {
        if (valid)
            logit = part[0][j] + part[1][j] + part[2][j] + part[3][j]
                  + part[4][j] + part[5][j] + part[6][j] + part[7][j];
        red[j] = logit;
    }
    __syncthreads();
    for (int off = 64; off; off >>= 1) {
        if (t < off) red[t] = fmaxf(red[t], red[t + off]);
        __syncthreads();
    }
    float m = red[0];
    __syncthreads();
    float e = (t < 128 && valid) ? __builtin_amdgcn_exp2f(1.44269504f * (logit - m)) : 0.0f;
    if (t < 128) red[j] = e;
    __syncthreads();
    for (int off = 64; off; off >>= 1) {
        if (t < off) red[t] += red[t + off];
        __syncthreads();
    }
    float s = red[0];
    if (t < 128 && j < N_) {
        size_t o = ((size_t)b * N_ + j) * 128 + i;
        spT_mid[o] = e / s;
        spT0[o] = (j == 1) ? 1.0f : 0.0f;
        spT5[o] = (j == len) ? 1.0f : 0.0f;
    }
}

// ============ per-layer aggregate: gates = q[j] + ve[i]; 512 thr ============
__global__ __launch_bounds__(512) void aggregate(const float* __restrict__ q,
        const float* __restrict__ ve, const float* __restrict__ spT,
        const float* __restrict__ p, const float* __restrict__ cc,
        const float* __restrict__ hc, float* __restrict__ cn,
        float* __restrict__ hn, float* __restrict__ pn) {
    __shared__ float qj[1024];
    __shared__ float wcol[128];
    __shared__ float red[128];
    __shared__ int vlist[128];
    __shared__ int nv_s;
    __shared__ float parts[2][2][H_];
    int t = threadIdx.x;             // 0..511
    int bj = blockIdx.x;
    int b = bj / N_, j = bj - b * N_;
    if (t < 128) {
        float wv = (t < N_) ? spT[(size_t)bj * 128 + t] * p[b * N_ + t] : 0.f;
        wcol[t] = wv;
        red[t] = wv;
    }
    __syncthreads();
    if (t == 0) {
        int nv = 0;
        for (int i = 0; i < N_; i++)
            if (wcol[i] != 0.0f) vlist[nv++] = i;
        nv_s = nv;
    }
    __syncthreads();
    for (int off = 64; off; off >>= 1) {
        if (t < off) red[t] += red[t + off];
        __syncthreads();
    }
    float wsum = red[0];
    if (wsum == 0.0f) {              // no mass reaches j: exact zeros
        if (t < 256) {
            cn[(size_t)bj * H_ + t] = 0.0f;
            hn[(size_t)bj * H_ + t] = 0.0f;
            if (t == 0) pn[bj] = 0.0f;
        }
        return;
    }
    qj[t] = q[(size_t)bj * 1024 + t];
    qj[512 + t] = q[(size_t)bj * 1024 + 512 + t];
    __syncthreads();
    int hh = t & 255, vs = t >> 8;
    int nv = nv_s;
    float ac = 0.f, ah = 0.f;
    for (int v = vs; v < nv; v += 2) {
        int i = vlist[v];
        float wv = wcol[i];
        size_t rowi = (size_t)b * N_ + i;
        if (j > i) {
            const float* vei = ve + rowi * 1024;
            float gi = qj[hh] + vei[hh];
            float gf = qj[256 + hh] + vei[256 + hh];
            float gg = qj[512 + hh] + vei[512 + hh];
            float go = qj[768 + hh] + vei[768 + hh];
            float c2 = cc[rowi * H_ + hh];
            float cp = sigm(gf) * c2 + sigm(gi) * tanh_f(gg);
            float hp = sigm(go) * tanh_f(cp);
            ac = fmaf(wv, cp, ac);
            ah = fmaf(wv, hp, ah);
        } else {
            ac = fmaf(wv, cc[rowi * H_ + hh], ac);
            ah = fmaf(wv, hc[rowi * H_ + hh], ah);
        }
    }
    parts[vs][0][hh] = ac;
    parts[vs][1][hh] = ah;
    __syncthreads();
    if (t < 256) {
        float inv = __builtin_amdgcn_rcpf(wsum + 1e-7f);
        cn[(size_t)bj * H_ + t] = (parts[0][0][t] + parts[1][0][t]) * inv;
        hn[(size_t)bj * H_ + t] = (parts[0][1][t] + parts[1][1][t]) * inv;
        if (t == 0) pn[bj] = wsum;
    }
}

// ---------------- host launcher ----------------

extern "C" void kernel_launch(void* const* d_in, const int* in_sizes, int n_in,
                              void* d_out, int out_size, void* d_ws, size_t ws_size,
                              hipStream_t stream) {
    const int*   code_statements = (const int*)d_in[0];
    const int*   code_length = (const int*)d_in[1];
    const float* embed = (const float*)d_in[2];
    const float* Wx_s = (const float*)d_in[3];
    const float* Wh_s = (const float*)d_in[4];
    const float* b_s  = (const float*)d_in[5];
    const float* W_se = (const float*)d_in[6];
    const float* b_se = (const float*)d_in[7];
    const float* Wx_e = (const float*)d_in[8];
    const float* Wh_e = (const float*)d_in[9];
    const float* b_e  = (const float*)d_in[10];
    const float* W_sd = (const float*)d_in[13];
    const float* b_sd = (const float*)d_in[14];
    const float* W_d1 = (const float*)d_in[15];
    // d_in[11] W_hk, d_in[12] b_hk, d_in[16] b_d1: softmax-invariant -> unused
    const float* init_a = (const float*)d_in[17];
    const float* init_b = (const float*)d_in[18];
    float* out = (float*)d_out;

    float* wsf = (float*)d_ws;
    size_t off = 0;
    auto alloc = [&](size_t n) { float* p = wsf + off; off += n; return p; };
    float* cz = alloc(1024);
    float* ck = alloc(256);
    float* xz = alloc((size_t)3072 * 1024);
    float* stmt = alloc(384 * 256);      // LSTM h buffer
    float* cls = alloc(384 * 256);       // LSTM cell state
    float* pref = alloc(R_ * 256);
    float* s_   = alloc(R_ * 256);       // pref @ W_se
    float* q  = alloc(R_ * 1024);
    float* r_ = alloc(R_ * 256);
    float* rT = alloc(4 * 256 * 128);
    float* ve = alloc(R_ * 1024);        // h@Wh_e + cz - q
    float* spT_mid = alloc(R_ * 128);
    float* spT0    = alloc(R_ * 128);
    float* spT5    = alloc(R_ * 128);
    float* p0 = alloc(R_);
    float* p1 = alloc(R_);
    float* c0 = alloc(R_ * 256);
    float* c1 = alloc(R_ * 256);
    float* h0 = alloc(R_ * 256);
    float* h1 = alloc(R_ * 256);

    // encoder critical path first
    gemm_t<32><<<dim3(8, 96), 256, 0, stream>>>(nullptr, code_statements, embed,
                                                Wx_s, b_s, nullptr, xz, 3072, 1024);
    bias_prep<<<dim3(5), 256, 0, stream>>>(b_se, Wx_e, b_e, W_sd, b_sd, cz, ck);
    init_state<<<dim3(R_), 256, 0, stream>>>(init_a, init_b, c0, h0, p0);
    for (int step = 0; step < T_; step++)
        lstm_step<<<dim3(16, 12), 256, 0, stream>>>(step, xz, Wh_s, stmt, cls);
    cumsum_k<<<dim3(4), 256, 0, stream>>>(stmt, pref);
    gemm_t<16><<<dim3(2, 25), 256, 0, stream>>>(pref, nullptr, nullptr, W_se, nullptr,
                                                nullptr, s_, R_, 256);
    qr_kernel<<<dim3(10, 25), 256, 0, stream>>>(s_, Wx_e, W_sd, q, r_, rT);
    softmax_once<<<dim3(R_), 1024, 0, stream>>>(r_, rT, ck, W_d1, code_length,
                                                spT_mid, spT0, spT5);
    // ve0 = h0@Wh_e + cz - q
    gemm_t<16><<<dim3(8, 25), 256, 0, stream>>>(h0, nullptr, nullptr, Wh_e, cz,
                                                q, ve, R_, 1024);

    // execution layers
    for (int layer = 0; layer < NL_; layer++) {
        bool odd = (layer & 1);
        float* pc = odd ? p1 : p0;
        float* pn = odd ? p0 : p1;
        float* cc = odd ? c1 : c0;
        float* cn = odd ? c0 : c1;
        float* hc = odd ? h1 : h0;
        float* hn = odd ? h0 : h1;
        if (layer == NL_ - 1) hn = out;  // final h straight to d_out
        const float* spT = (layer == 0) ? spT0 : (layer == NL_ - 1) ? spT5 : spT_mid;
        aggregate<<<dim3(R_), 512, 0, stream>>>(q, ve, spT, pc, cc, hc, cn, hn, pn);
        if (layer < NL_ - 1)
            gemm_t<16><<<dim3(8, 25), 256, 0, stream>>>(hn, nullptr, nullptr, Wh_e, cz,
                                                        q, ve, R_, 1024);
    }
}

// Round 10
// 414.761 us; speedup vs baseline: 3.2368x; 1.0993x over previous
//
#include <hip/hip_runtime.h>
#include <cstddef>

// Problem constants
#define B_   4
#define NS_  96
#define T_   8
#define H_   256
#define N_   97      // NS + 1
#define NL_  6       // NUM_LAYERS
#define R_   388     // B_ * N_

// fast gates: v_exp_f32 (2^x) + v_rcp_f32
__device__ __forceinline__ float sigm(float x) {
    return __builtin_amdgcn_rcpf(1.0f + __builtin_amdgcn_exp2f(-1.44269504f * x));
}
__device__ __forceinline__ float tanh_f(float x) {
    return 1.0f - 2.0f * __builtin_amdgcn_rcpf(1.0f + __builtin_amdgcn_exp2f(2.88539008f * x));
}

// ============ prologue: xz GEMM + cz/ck/hw preps + state init, one launch ============
// bid<768: xz tiles; 768-771: cz; 772-775: hw = init_b@Wh_e + cz; 776: ck; 777+: init.
__global__ __launch_bounds__(256) void prologue(
        const int* __restrict__ ids, const float* __restrict__ embed,
        const float* __restrict__ Wx_s, const float* __restrict__ b_s,
        const float* __restrict__ b_se, const float* __restrict__ Wx_e,
        const float* __restrict__ b_e, const float* __restrict__ W_sd,
        const float* __restrict__ b_sd, const float* __restrict__ Wh_e,
        const float* __restrict__ init_a, const float* __restrict__ init_b,
        float* __restrict__ xz, float* __restrict__ cz, float* __restrict__ ck,
        float* __restrict__ hw, float* __restrict__ c0, float* __restrict__ h0,
        float* __restrict__ p0) {
    int bid = blockIdx.x, t = threadIdx.x;
    if (bid < 768) {                      // xz = embed[ids] @ Wx_s + b_s
        __shared__ float As[32][260];
        __shared__ int ridx[32];
        int r0 = (bid >> 3) * 32, n0 = (bid & 7) * 128;
        if (t < 32) ridx[t] = ids[r0 + t];
        __syncthreads();
#pragma unroll
        for (int m = 0; m < 8; m++) {
            int L = m * 256 + t;
            int r = L >> 6, c4 = (L & 63) * 4;
            *(float4*)&As[r][c4] = *(const float4*)(embed + (size_t)ridx[r] * 256 + c4);
        }
        __syncthreads();
        int rg = t >> 5, cg = t & 31;
        float acc[4][4] = {};
        const float* wp = Wx_s + n0 + 4 * cg;
#pragma unroll 2
        for (int kb = 0; kb < 64; kb++) {
            float4 w0 = *(const float4*)(wp + (size_t)(4 * kb + 0) * 1024);
            float4 w1 = *(const float4*)(wp + (size_t)(4 * kb + 1) * 1024);
            float4 w2 = *(const float4*)(wp + (size_t)(4 * kb + 2) * 1024);
            float4 w3 = *(const float4*)(wp + (size_t)(4 * kb + 3) * 1024);
#pragma unroll
            for (int i = 0; i < 4; i++) {
                float4 a = *(const float4*)&As[rg * 4 + i][4 * kb];
                acc[i][0] = fmaf(a.x, w0.x, acc[i][0]);
                acc[i][1] = fmaf(a.x, w0.y, acc[i][1]);
                acc[i][2] = fmaf(a.x, w0.z, acc[i][2]);
                acc[i][3] = fmaf(a.x, w0.w, acc[i][3]);
                acc[i][0] = fmaf(a.y, w1.x, acc[i][0]);
                acc[i][1] = fmaf(a.y, w1.y, acc[i][1]);
                acc[i][2] = fmaf(a.y, w1.z, acc[i][2]);
                acc[i][3] = fmaf(a.y, w1.w, acc[i][3]);
                acc[i][0] = fmaf(a.z, w2.x, acc[i][0]);
                acc[i][1] = fmaf(a.z, w2.y, acc[i][1]);
                acc[i][2] = fmaf(a.z, w2.z, acc[i][2]);
                acc[i][3] = fmaf(a.z, w2.w, acc[i][3]);
                acc[i][0] = fmaf(a.w, w3.x, acc[i][0]);
                acc[i][1] = fmaf(a.w, w3.y, acc[i][1]);
                acc[i][2] = fmaf(a.w, w3.z, acc[i][2]);
                acc[i][3] = fmaf(a.w, w3.w, acc[i][3]);
            }
        }
        int col = n0 + 4 * cg;
        float4 bv = *(const float4*)&b_s[col];
#pragma unroll
        for (int i = 0; i < 4; i++) {
            int r = r0 + rg * 4 + i;
            float4 o = make_float4(acc[i][0] + bv.x, acc[i][1] + bv.y,
                                   acc[i][2] + bv.z, acc[i][3] + bv.w);
            *(float4*)&xz[(size_t)r * 1024 + col] = o;
        }
    } else if (bid < 772) {               // cz[n] = b_e + b_se@Wx_e
        int n = (bid - 768) * 256 + t;
        float acc = b_e[n];
        for (int k = 0; k < 256; k++) acc = fmaf(b_se[k], Wx_e[(size_t)k * 1024 + n], acc);
        cz[n] = acc;
    } else if (bid < 776) {               // hw[n] = cz[n] + init_b@Wh_e (computed independently)
        int n = (bid - 772) * 256 + t;
        float acc = b_e[n];
        for (int k = 0; k < 256; k++) {
            acc = fmaf(b_se[k], Wx_e[(size_t)k * 1024 + n], acc);
            acc = fmaf(init_b[k], Wh_e[(size_t)k * 1024 + n], acc);
        }
        hw[n] = acc;
    } else if (bid == 776) {              // ck[n] = b_sd + b_se@W_sd
        float acc = b_sd[t];
        for (int k = 0; k < 256; k++) acc = fmaf(b_se[k], W_sd[(size_t)k * 256 + t], acc);
        ck[t] = acc;
    } else {                              // init c0/h0/p0: 97 blocks x 4 rows
        int r0 = (bid - 777) * 4;
        float ia = init_a[t], ib = init_b[t];
#pragma unroll
        for (int rr = 0; rr < 4; rr++) {
            int row = r0 + rr;
            c0[(size_t)row * 256 + t] = ia;
            h0[(size_t)row * 256 + t] = ib;
            if (t == 0) p0[row] = ((row % N_) == 0) ? 1.0f : 0.0f;
        }
    }
}

// ============ templated GEMM: C = A@W (+bias)(-subQ), p-gated rows, MT x 128 tile ============
template<int MT>
__global__ __launch_bounds__(256) void gemm_t(const float* __restrict__ A,
        const float* __restrict__ W, const float* __restrict__ bias,
        const float* __restrict__ subQ, const float* __restrict__ pgate,
        float* __restrict__ C, int R, int NC) {
    __shared__ float As[MT][260];
    __shared__ int anyflag;
    int t = threadIdx.x;
    int n0 = blockIdx.x * 128;
    int r0 = blockIdx.y * MT;
    if (pgate) {                          // skip blocks whose rows all have p == 0
        if (t == 0) anyflag = 0;
        __syncthreads();
        if (t < MT && r0 + t < R && pgate[r0 + t] != 0.0f) anyflag = 1;
        __syncthreads();
        if (!anyflag) return;
    }
#pragma unroll
    for (int m = 0; m < MT / 4; m++) {
        int L = m * 256 + t;
        int r = L >> 6, c4 = (L & 63) * 4;
        int rr = r0 + r;
        float4 v = make_float4(0.f, 0.f, 0.f, 0.f);
        if (rr < R) v = *(const float4*)(A + (size_t)rr * 256 + c4);
        *(float4*)&As[r][c4] = v;
    }
    __syncthreads();
    constexpr int RT = MT / 8;
    int rg = t >> 5, cg = t & 31;
    float acc[RT][4] = {};
    const float* wp = W + n0 + 4 * cg;
#pragma unroll 2
    for (int kb = 0; kb < 64; kb++) {
        float4 w0 = *(const float4*)(wp + (size_t)(4 * kb + 0) * NC);
        float4 w1 = *(const float4*)(wp + (size_t)(4 * kb + 1) * NC);
        float4 w2 = *(const float4*)(wp + (size_t)(4 * kb + 2) * NC);
        float4 w3 = *(const float4*)(wp + (size_t)(4 * kb + 3) * NC);
#pragma unroll
        for (int i = 0; i < RT; i++) {
            float4 a = *(const float4*)&As[rg * RT + i][4 * kb];
            acc[i][0] = fmaf(a.x, w0.x, acc[i][0]);
            acc[i][1] = fmaf(a.x, w0.y, acc[i][1]);
            acc[i][2] = fmaf(a.x, w0.z, acc[i][2]);
            acc[i][3] = fmaf(a.x, w0.w, acc[i][3]);
            acc[i][0] = fmaf(a.y, w1.x, acc[i][0]);
            acc[i][1] = fmaf(a.y, w1.y, acc[i][1]);
            acc[i][2] = fmaf(a.y, w1.z, acc[i][2]);
            acc[i][3] = fmaf(a.y, w1.w, acc[i][3]);
            acc[i][0] = fmaf(a.z, w2.x, acc[i][0]);
            acc[i][1] = fmaf(a.z, w2.y, acc[i][1]);
            acc[i][2] = fmaf(a.z, w2.z, acc[i][2]);
            acc[i][3] = fmaf(a.z, w2.w, acc[i][3]);
            acc[i][0] = fmaf(a.w, w3.x, acc[i][0]);
            acc[i][1] = fmaf(a.w, w3.y, acc[i][1]);
            acc[i][2] = fmaf(a.w, w3.z, acc[i][2]);
            acc[i][3] = fmaf(a.w, w3.w, acc[i][3]);
        }
    }
    int col = n0 + 4 * cg;
    float4 bv = make_float4(0.f, 0.f, 0.f, 0.f);
    if (bias) bv = *(const float4*)&bias[col];
#pragma unroll
    for (int i = 0; i < RT; i++) {
        int r = r0 + rg * RT + i;
        if (r < R) {
            float4 o = make_float4(acc[i][0] + bv.x, acc[i][1] + bv.y,
                                   acc[i][2] + bv.z, acc[i][3] + bv.w);
            if (subQ) {
                float4 s4 = *(const float4*)(subQ + (size_t)r * NC + col);
                o.x -= s4.x; o.y -= s4.y; o.z -= s4.z; o.w -= s4.w;
            }
            *(float4*)&C[(size_t)r * NC + col] = o;
        }
    }
}

// ============ merged q/r GEMM: bx<8 -> q (and ve0 = hw - q); else r (+rT) ============
__global__ __launch_bounds__(256) void qr_kernel(const float* __restrict__ S,
        const float* __restrict__ Wx_e, const float* __restrict__ W_sd,
        const float* __restrict__ hw, float* __restrict__ q, float* __restrict__ ve0,
        float* __restrict__ r_, float* __restrict__ rT) {
    __shared__ float As[16][260];
    int t = threadIdx.x;
    int bx = blockIdx.x;
    int r0 = blockIdx.y * 16;
#pragma unroll
    for (int m = 0; m < 4; m++) {
        int L = m * 256 + t;
        int r = L >> 6, c4 = (L & 63) * 4;
        int rr = r0 + r;
        float4 v = make_float4(0.f, 0.f, 0.f, 0.f);
        if (rr < R_) v = *(const float4*)(S + (size_t)rr * 256 + c4);
        *(float4*)&As[r][c4] = v;
    }
    __syncthreads();
    bool isq = bx < 8;
    const float* W = isq ? Wx_e : W_sd;
    int NC = isq ? 1024 : 256;
    int n0 = (isq ? bx : bx - 8) * 128;
    int rg = t >> 5, cg = t & 31;
    float acc[2][4] = {};
    const float* wp = W + n0 + 4 * cg;
#pragma unroll 2
    for (int kb = 0; kb < 64; kb++) {
        float4 w0 = *(const float4*)(wp + (size_t)(4 * kb + 0) * NC);
        float4 w1 = *(const float4*)(wp + (size_t)(4 * kb + 1) * NC);
        float4 w2 = *(const float4*)(wp + (size_t)(4 * kb + 2) * NC);
        float4 w3 = *(const float4*)(wp + (size_t)(4 * kb + 3) * NC);
#pragma unroll
        for (int i = 0; i < 2; i++) {
            float4 a = *(const float4*)&As[rg * 2 + i][4 * kb];
            acc[i][0] = fmaf(a.x, w0.x, acc[i][0]);
            acc[i][1] = fmaf(a.x, w0.y, acc[i][1]);
            acc[i][2] = fmaf(a.x, w0.z, acc[i][2]);
            acc[i][3] = fmaf(a.x, w0.w, acc[i][3]);
            acc[i][0] = fmaf(a.y, w1.x, acc[i][0]);
            acc[i][1] = fmaf(a.y, w1.y, acc[i][1]);
            acc[i][2] = fmaf(a.y, w1.z, acc[i][2]);
            acc[i][3] = fmaf(a.y, w1.w, acc[i][3]);
            acc[i][0] = fmaf(a.z, w2.x, acc[i][0]);
            acc[i][1] = fmaf(a.z, w2.y, acc[i][1]);
            acc[i][2] = fmaf(a.z, w2.z, acc[i][2]);
            acc[i][3] = fmaf(a.z, w2.w, acc[i][3]);
            acc[i][0] = fmaf(a.w, w3.x, acc[i][0]);
            acc[i][1] = fmaf(a.w, w3.y, acc[i][1]);
            acc[i][2] = fmaf(a.w, w3.z, acc[i][2]);
            acc[i][3] = fmaf(a.w, w3.w, acc[i][3]);
        }
    }
    int col = n0 + 4 * cg;
#pragma unroll
    for (int i = 0; i < 2; i++) {
        int r = r0 + rg * 2 + i;
        if (r < R_) {
            float4 o = make_float4(acc[i][0], acc[i][1], acc[i][2], acc[i][3]);
            if (isq) {
                *(float4*)&q[(size_t)r * 1024 + col] = o;
                float4 hwv = *(const float4*)&hw[col];   // ve0 = hw - q (h0 rows identical)
                float4 v0 = make_float4(hwv.x - o.x, hwv.y - o.y, hwv.z - o.z, hwv.w - o.w);
                *(float4*)&ve0[(size_t)r * 1024 + col] = v0;
            } else {
                *(float4*)&r_[(size_t)r * 256 + col] = o;
                int b = r / N_, n = r - b * N_;
                rT[((size_t)b * 256 + col + 0) * 128 + n] = o.x;
                rT[((size_t)b * 256 + col + 1) * 128 + n] = o.y;
                rT[((size_t)b * 256 + col + 2) * 128 + n] = o.z;
                rT[((size_t)b * 256 + col + 3) * 128 + n] = o.w;
            }
        }
    }
}

// ============ LSTM steps 0+1 fused: h0 computed in-LDS, then step-1 GEMM ============
__global__ __launch_bounds__(256) void lstm_first(const float* __restrict__ xz,
        const float* __restrict__ Wh, float* __restrict__ hbuf, float* __restrict__ cbuf) {
    __shared__ float Wh_s[256][64];
    __shared__ float h_s[32][260];
    __shared__ float zs[32][68];
    int t = threadIdx.x;
    int ct = blockIdx.x, st = blockIdx.y;
    int et0 = ct * 16, s0 = st * 32;
    // stage Wh slice
#pragma unroll
    for (int m = 0; m < 16; m++) {
        int L = m * 256 + t;
        int k = L >> 4, f = L & 15;
        int gg = f >> 2, qq = f & 3;
        *(float4*)&Wh_s[k][f * 4] = *(const float4*)&Wh[(size_t)k * 1024 + gg * 256 + et0 + qq * 4];
    }
    // step 0 (h=0, c=0): h0 for all 32 seqs x 256 cols from xz step 0
    for (int seq = 0; seq < 32; seq++) {
        const float* z0 = xz + ((size_t)(s0 + seq) * T_) * 1024;
        float gi = z0[t], gg = z0[512 + t], go = z0[768 + t];
        float c0v = sigm(gi) * tanh_f(gg);
        h_s[seq][t] = sigm(go) * tanh_f(c0v);
    }
    // own cells' c after step 0 (2 per thread)
    float creg[2];
    {
        int sqA = t >> 4, e = et0 + (t & 15);
#pragma unroll
        for (int u = 0; u < 2; u++) {
            const float* z0 = xz + ((size_t)(s0 + sqA + u * 16) * T_) * 1024;
            creg[u] = sigm(z0[e]) * tanh_f(z0[512 + e]);
        }
    }
    __syncthreads();
    // step 1 GEMM
    {
        int sp = (t >> 4) & 15, cq = t & 15;
        int kg = t >> 8;  (void)kg;
        int g = cq >> 2, q4 = cq & 3;
        int gcol = g * 256 + et0 + q4 * 4;
        float4 a0 = *(const float4*)(xz + ((size_t)(s0 + sp) * T_ + 1) * 1024 + gcol);
        float4 a1 = *(const float4*)(xz + ((size_t)(s0 + sp + 16) * T_ + 1) * 1024 + gcol);
#pragma unroll 4
        for (int k = 0; k < 256; k++) {
            float4 w4 = *(const float4*)&Wh_s[k][cq * 4];
            float hA = h_s[sp][k];
            float hB = h_s[sp + 16][k];
            a0.x = fmaf(hA, w4.x, a0.x); a0.y = fmaf(hA, w4.y, a0.y);
            a0.z = fmaf(hA, w4.z, a0.z); a0.w = fmaf(hA, w4.w, a0.w);
            a1.x = fmaf(hB, w4.x, a1.x); a1.y = fmaf(hB, w4.y, a1.y);
            a1.z = fmaf(hB, w4.z, a1.z); a1.w = fmaf(hB, w4.w, a1.w);
        }
        *(float4*)&zs[sp][cq * 4] = a0;
        *(float4*)&zs[sp + 16][cq * 4] = a1;
    }
    __syncthreads();
    {
        int sqA = t >> 4, e = t & 15;
#pragma unroll
        for (int u = 0; u < 2; u++) {
            int seq = sqA + u * 16;
            float gi = zs[seq][e], gf = zs[seq][16 + e], gg = zs[seq][32 + e], go = zs[seq][48 + e];
            float cn = sigm(gf) * creg[u] + sigm(gi) * tanh_f(gg);
            size_t gidx = (size_t)(s0 + seq) * H_ + et0 + e;
            cbuf[gidx] = cn;
            hbuf[gidx] = sigm(go) * tanh_f(cn);
        }
    }
}

// ============ LSTM one step (steps 2..7) ============
__global__ __launch_bounds__(256) void lstm_step(int step, const float* __restrict__ xz,
        const float* __restrict__ Wh, float* __restrict__ hbuf, float* __restrict__ cbuf) {
    __shared__ float Wh_s[256][64];
    __shared__ float h_s[32][260];
    __shared__ float zs[32][68];
    int t = threadIdx.x;
    int ct = blockIdx.x, st = blockIdx.y;
    int et0 = ct * 16, s0 = st * 32;
    int sp = t >> 4, cq = t & 15;
    int g = cq >> 2, q4 = cq & 3;
    int gcol = g * 256 + et0 + q4 * 4;
    float4 a0 = *(const float4*)(xz + ((size_t)(s0 + sp) * T_ + step) * 1024 + gcol);
    float4 a1 = *(const float4*)(xz + ((size_t)(s0 + sp + 16) * T_ + step) * 1024 + gcol);
#pragma unroll
    for (int m = 0; m < 16; m++) {
        int L = m * 256 + t;
        int k = L >> 4, f = L & 15;
        int gg = f >> 2, qq = f & 3;
        *(float4*)&Wh_s[k][f * 4] = *(const float4*)&Wh[(size_t)k * 1024 + gg * 256 + et0 + qq * 4];
    }
#pragma unroll
    for (int m = 0; m < 8; m++) {
        int L = m * 256 + t;
        int seq = L >> 6, c4 = (L & 63) * 4;
        *(float4*)&h_s[seq][c4] = *(const float4*)&hbuf[(size_t)(s0 + seq) * H_ + c4];
    }
    __syncthreads();
#pragma unroll 4
    for (int k = 0; k < 256; k++) {
        float4 w4 = *(const float4*)&Wh_s[k][cq * 4];
        float h0 = h_s[sp][k];
        float h1 = h_s[sp + 16][k];
        a0.x = fmaf(h0, w4.x, a0.x); a0.y = fmaf(h0, w4.y, a0.y);
        a0.z = fmaf(h0, w4.z, a0.z); a0.w = fmaf(h0, w4.w, a0.w);
        a1.x = fmaf(h1, w4.x, a1.x); a1.y = fmaf(h1, w4.y, a1.y);
        a1.z = fmaf(h1, w4.z, a1.z); a1.w = fmaf(h1, w4.w, a1.w);
    }
    *(float4*)&zs[sp][cq * 4] = a0;
    *(float4*)&zs[sp + 16][cq * 4] = a1;
    __syncthreads();
    int seqA = t >> 4, e = t & 15;
#pragma unroll
    for (int u = 0; u < 2; u++) {
        int seq = seqA + u * 16;
        float gi = zs[seq][e], gf = zs[seq][16 + e], gg = zs[seq][32 + e], go = zs[seq][48 + e];
        size_t gidx = (size_t)(s0 + seq) * H_ + et0 + e;
        float cnew = sigm(gf) * cbuf[gidx] + sigm(gi) * tanh_f(gg);
        cbuf[gidx] = cnew;
        hbuf[gidx] = sigm(go) * tanh_f(cnew);
    }
}

// ============ prefix sums over statements ============
__global__ void cumsum_k(const float* __restrict__ stmt, float* __restrict__ pref) {
    int b = blockIdx.x, t = threadIdx.x;
    float run = 0.0f;
    pref[((size_t)b * N_) * H_ + t] = 0.0f;
    for (int n = 1; n < N_; n++) {
        run += stmt[((size_t)b * NS_ + n - 1) * H_ + t];
        pref[((size_t)b * N_ + n) * H_ + t] = run;
    }
}

// ============ ONCE: logits + masked softmax (layer-invariant) ============
__global__ void softmax_once(const float* __restrict__ r, const float* __restrict__ rT,
                             const float* __restrict__ ck, const float* __restrict__ Wd1,
                             const int* __restrict__ code_length,
                             float* __restrict__ spT_mid, float* __restrict__ spT0,
                             float* __restrict__ spT5) {
    __shared__ float ri[H_], ckl[H_], wd[H_];
    __shared__ float part[8][128];
    __shared__ float red[128];
    int t = threadIdx.x;             // 0..1023
    int j = t & 127, half = t >> 7;
    int bi = blockIdx.x;
    int b = bi / N_, i = bi % N_;
    if (t < H_) {
        ri[t] = r[(size_t)bi * H_ + t];
        ckl[t] = ck[t];
        wd[t] = Wd1[256 + t];
    }
    __syncthreads();
    int len = code_length[b] / T_;
    bool valid = (j < N_) && ((j > i && j <= len) || (j == len));
    float acc = 0.0f;
    if (valid) {
        const float* rTb = rT + (size_t)b * H_ * 128 + j;
        int h0 = half * 32;
#pragma unroll 4
        for (int hh = 0; hh < 32; hh++) {
            int h = h0 + hh;
            float v = rTb[(size_t)h * 128] - ri[h] + ckl[h];
            acc = fmaf(fmaxf(v, 0.0f), wd[h], acc);
        }
    }
    part[half][j] = acc;
    __syncthreads();
    float logit = -3.0e38f;
    if (t < 128) {
        if (valid)
            logit = part[0][j] + part[1][j] + part[2][j] + part[3][j]
                  + part[4][j] + part[5][j] + part[6][j] + part[7][j];
        red[j] = logit;
    }
    __syncthreads();
    for (int off = 64; off; off >>= 1) {
        if (t < off) red[t] = fmaxf(red[t], red[t + off]);
        __syncthreads();
    }
    float m = red[0];
    __syncthreads();
    float e = (t < 128 && valid) ? __builtin_amdgcn_exp2f(1.44269504f * (logit - m)) : 0.0f;
    if (t < 128) red[j] = e;
    __syncthreads();
    for (int off = 64; off; off >>= 1) {
        if (t < off) red[t] += red[t + off];
        __syncthreads();
    }
    float s = red[0];
    if (t < 128 && j < N_) {
        size_t o = ((size_t)b * N_ + j) * 128 + i;
        spT_mid[o] = e / s;
        spT0[o] = (j == 1) ? 1.0f : 0.0f;
        spT5[o] = (j == len) ? 1.0f : 0.0f;
    }
}

// ============ per-layer aggregate: gates = q[j] + ve[i]; 512 thr ============
__global__ __launch_bounds__(512) void aggregate(const float* __restrict__ q,
        const float* __restrict__ ve, const float* __restrict__ spT,
        const float* __restrict__ p, const float* __restrict__ cc,
        const float* __restrict__ hc, float* __restrict__ cn,
        float* __restrict__ hn, float* __restrict__ pn) {
    __shared__ float qj[1024];
    __shared__ float wcol[128];
    __shared__ float red[128];
    __shared__ int vlist[128];
    __shared__ int nv_s;
    __shared__ float parts[2][2][H_];
    int t = threadIdx.x;
    int bj = blockIdx.x;
    int b = bj / N_, j = bj - b * N_;
    if (t < 128) {
        float wv = (t < N_) ? spT[(size_t)bj * 128 + t] * p[b * N_ + t] : 0.f;
        wcol[t] = wv;
        red[t] = wv;
    }
    __syncthreads();
    if (t == 0) {
        int nv = 0;
        for (int i = 0; i < N_; i++)
            if (wcol[i] != 0.0f) vlist[nv++] = i;
        nv_s = nv;
    }
    __syncthreads();
    for (int off = 64; off; off >>= 1) {
        if (t < off) red[t] += red[t + off];
        __syncthreads();
    }
    float wsum = red[0];
    if (wsum == 0.0f) {
        if (t < 256) {
            cn[(size_t)bj * H_ + t] = 0.0f;
            hn[(size_t)bj * H_ + t] = 0.0f;
            if (t == 0) pn[bj] = 0.0f;
        }
        return;
    }
    qj[t] = q[(size_t)bj * 1024 + t];
    qj[512 + t] = q[(size_t)bj * 1024 + 512 + t];
    __syncthreads();
    int hh = t & 255, vs = t >> 8;
    int nv = nv_s;
    float ac = 0.f, ah = 0.f;
    for (int v = vs; v < nv; v += 2) {
        int i = vlist[v];
        float wv = wcol[i];
        size_t rowi = (size_t)b * N_ + i;
        if (j > i) {
            const float* vei = ve + rowi * 1024;
            float gi = qj[hh] + vei[hh];
            float gf = qj[256 + hh] + vei[256 + hh];
            float gg = qj[512 + hh] + vei[512 + hh];
            float go = qj[768 + hh] + vei[768 + hh];
            float c2 = cc[rowi * H_ + hh];
            float cp = sigm(gf) * c2 + sigm(gi) * tanh_f(gg);
            float hp = sigm(go) * tanh_f(cp);
            ac = fmaf(wv, cp, ac);
            ah = fmaf(wv, hp, ah);
        } else {
            ac = fmaf(wv, cc[rowi * H_ + hh], ac);
            ah = fmaf(wv, hc[rowi * H_ + hh], ah);
        }
    }
    parts[vs][0][hh] = ac;
    parts[vs][1][hh] = ah;
    __syncthreads();
    if (t < 256) {
        float inv = __builtin_amdgcn_rcpf(wsum + 1e-7f);
        cn[(size_t)bj * H_ + t] = (parts[0][0][t] + parts[1][0][t]) * inv;
        hn[(size_t)bj * H_ + t] = (parts[0][1][t] + parts[1][1][t]) * inv;
        if (t == 0) pn[bj] = wsum;
    }
}

// ---------------- host launcher ----------------

extern "C" void kernel_launch(void* const* d_in, const int* in_sizes, int n_in,
                              void* d_out, int out_size, void* d_ws, size_t ws_size,
                              hipStream_t stream) {
    const int*   code_statements = (const int*)d_in[0];
    const int*   code_length = (const int*)d_in[1];
    const float* embed = (const float*)d_in[2];
    const float* Wx_s = (const float*)d_in[3];
    const float* Wh_s = (const float*)d_in[4];
    const float* b_s  = (const float*)d_in[5];
    const float* W_se = (const float*)d_in[6];
    const float* b_se = (const float*)d_in[7];
    const float* Wx_e = (const float*)d_in[8];
    const float* Wh_e = (const float*)d_in[9];
    const float* b_e  = (const float*)d_in[10];
    const float* W_sd = (const float*)d_in[13];
    const float* b_sd = (const float*)d_in[14];
    const float* W_d1 = (const float*)d_in[15];
    // d_in[11] W_hk, d_in[12] b_hk, d_in[16] b_d1: softmax-invariant -> unused
    const float* init_a = (const float*)d_in[17];
    const float* init_b = (const float*)d_in[18];
    float* out = (float*)d_out;

    float* wsf = (float*)d_ws;
    size_t off = 0;
    auto alloc = [&](size_t n) { float* p = wsf + off; off += n; return p; };
    float* cz = alloc(1024);
    float* ck = alloc(256);
    float* hw = alloc(1024);             // init_b@Wh_e + cz
    float* xz = alloc((size_t)3072 * 1024);
    float* stmt = alloc(384 * 256);      // LSTM h buffer
    float* cls = alloc(384 * 256);       // LSTM cell state
    float* pref = alloc(R_ * 256);
    float* s_   = alloc(R_ * 256);       // pref @ W_se
    float* q  = alloc(R_ * 1024);
    float* r_ = alloc(R_ * 256);
    float* rT = alloc(4 * 256 * 128);
    float* ve = alloc(R_ * 1024);        // h@Wh_e + cz - q
    float* spT_mid = alloc(R_ * 128);
    float* spT0    = alloc(R_ * 128);
    float* spT5    = alloc(R_ * 128);
    float* p0 = alloc(R_);
    float* p1 = alloc(R_);
    float* c0 = alloc(R_ * 256);
    float* c1 = alloc(R_ * 256);
    float* h0 = alloc(R_ * 256);
    float* h1 = alloc(R_ * 256);

    // one prologue launch: xz + cz/ck/hw + init state
    prologue<<<dim3(874), 256, 0, stream>>>(code_statements, embed, Wx_s, b_s,
                                            b_se, Wx_e, b_e, W_sd, b_sd, Wh_e,
                                            init_a, init_b, xz, cz, ck, hw, c0, h0, p0);
    // LSTM: steps 0+1 fused, then 2..7
    lstm_first<<<dim3(16, 12), 256, 0, stream>>>(xz, Wh_s, stmt, cls);
    for (int step = 2; step < T_; step++)
        lstm_step<<<dim3(16, 12), 256, 0, stream>>>(step, xz, Wh_s, stmt, cls);
    cumsum_k<<<dim3(4), 256, 0, stream>>>(stmt, pref);
    gemm_t<16><<<dim3(2, 25), 256, 0, stream>>>(pref, W_se, nullptr, nullptr, nullptr,
                                                s_, R_, 256);
    qr_kernel<<<dim3(10, 25), 256, 0, stream>>>(s_, Wx_e, W_sd, hw, q, ve, r_, rT);
    softmax_once<<<dim3(R_), 1024, 0, stream>>>(r_, rT, ck, W_d1, code_length,
                                                spT_mid, spT0, spT5);

    // execution layers (ve0 already produced by qr_kernel)
    for (int layer = 0; layer < NL_; layer++) {
        bool odd = (layer & 1);
        float* pc = odd ? p1 : p0;
        float* pn = odd ? p0 : p1;
        float* cc = odd ? c1 : c0;
        float* cn = odd ? c0 : c1;
        float* hc = odd ? h1 : h0;
        float* hn = odd ? h0 : h1;
        if (layer == NL_ - 1) hn = out;  // final h straight to d_out
        const float* spT = (layer == 0) ? spT0 : (layer == NL_ - 1) ? spT5 : spT_mid;
        aggregate<<<dim3(R_), 512, 0, stream>>>(q, ve, spT, pc, cc, hc, cn, hn, pn);
        if (layer < NL_ - 1)
            gemm_t<16><<<dim3(8, 25), 256, 0, stream>>>(hn, Wh_e, cz, q, pn,
                                                        ve, R_, 1024);
    }
}

// Round 11
// 410.964 us; speedup vs baseline: 3.2667x; 1.0092x over previous
//
#include <hip/hip_runtime.h>
#include <cstddef>

// Problem constants
#define B_   4
#define NS_  96
#define T_   8
#define H_   256
#define N_   97      // NS + 1
#define NL_  6       // NUM_LAYERS
#define R_   388     // B_ * N_

// fast gates: v_exp_f32 (2^x) + v_rcp_f32
__device__ __forceinline__ float sigm(float x) {
    return __builtin_amdgcn_rcpf(1.0f + __builtin_amdgcn_exp2f(-1.44269504f * x));
}
__device__ __forceinline__ float tanh_f(float x) {
    return 1.0f - 2.0f * __builtin_amdgcn_rcpf(1.0f + __builtin_amdgcn_exp2f(2.88539008f * x));
}

// ============ prologue v2: 512-thr blocks ============
// bid<384: xz 64x128 tiles; 384-385: cz; 386-387: hw; 388: ck; 389..437: init (8 rows each).
__global__ __launch_bounds__(512) void prologue(
        const int* __restrict__ ids, const float* __restrict__ embed,
        const float* __restrict__ Wx_s, const float* __restrict__ b_s,
        const float* __restrict__ b_se, const float* __restrict__ Wx_e,
        const float* __restrict__ b_e, const float* __restrict__ W_sd,
        const float* __restrict__ b_sd, const float* __restrict__ Wh_e,
        const float* __restrict__ init_a, const float* __restrict__ init_b,
        float* __restrict__ xz, float* __restrict__ cz, float* __restrict__ ck,
        float* __restrict__ hw, float* __restrict__ c0, float* __restrict__ h0,
        float* __restrict__ p0) {
    int bid = blockIdx.x, t = threadIdx.x;
    if (bid < 384) {                      // xz = embed[ids] @ Wx_s + b_s, 64x128 tile
        __shared__ float As[64][260];
        __shared__ int ridx[64];
        int r0 = (bid >> 3) * 64, n0 = (bid & 7) * 128;
        if (t < 64) ridx[t] = ids[r0 + t];
        __syncthreads();
#pragma unroll
        for (int m = 0; m < 8; m++) {     // stage 64x256 (8 float4/thread)
            int L = m * 512 + t;
            int r = L >> 6, c4 = (L & 63) * 4;
            *(float4*)&As[r][c4] = *(const float4*)(embed + (size_t)ridx[r] * 256 + c4);
        }
        __syncthreads();
        int rg = t >> 5, cg = t & 31;     // 16 row-groups x 32 col-quads
        float acc[4][4] = {};
        const float* wp = Wx_s + n0 + 4 * cg;
#pragma unroll 2
        for (int kb = 0; kb < 64; kb++) {
            float4 w0 = *(const float4*)(wp + (size_t)(4 * kb + 0) * 1024);
            float4 w1 = *(const float4*)(wp + (size_t)(4 * kb + 1) * 1024);
            float4 w2 = *(const float4*)(wp + (size_t)(4 * kb + 2) * 1024);
            float4 w3 = *(const float4*)(wp + (size_t)(4 * kb + 3) * 1024);
#pragma unroll
            for (int i = 0; i < 4; i++) {
                float4 a = *(const float4*)&As[rg * 4 + i][4 * kb];
                acc[i][0] = fmaf(a.x, w0.x, acc[i][0]);
                acc[i][1] = fmaf(a.x, w0.y, acc[i][1]);
                acc[i][2] = fmaf(a.x, w0.z, acc[i][2]);
                acc[i][3] = fmaf(a.x, w0.w, acc[i][3]);
                acc[i][0] = fmaf(a.y, w1.x, acc[i][0]);
                acc[i][1] = fmaf(a.y, w1.y, acc[i][1]);
                acc[i][2] = fmaf(a.y, w1.z, acc[i][2]);
                acc[i][3] = fmaf(a.y, w1.w, acc[i][3]);
                acc[i][0] = fmaf(a.z, w2.x, acc[i][0]);
                acc[i][1] = fmaf(a.z, w2.y, acc[i][1]);
                acc[i][2] = fmaf(a.z, w2.z, acc[i][2]);
                acc[i][3] = fmaf(a.z, w2.w, acc[i][3]);
                acc[i][0] = fmaf(a.w, w3.x, acc[i][0]);
                acc[i][1] = fmaf(a.w, w3.y, acc[i][1]);
                acc[i][2] = fmaf(a.w, w3.z, acc[i][2]);
                acc[i][3] = fmaf(a.w, w3.w, acc[i][3]);
            }
        }
        int col = n0 + 4 * cg;
        float4 bv = *(const float4*)&b_s[col];
#pragma unroll
        for (int i = 0; i < 4; i++) {
            int r = r0 + rg * 4 + i;
            float4 o = make_float4(acc[i][0] + bv.x, acc[i][1] + bv.y,
                                   acc[i][2] + bv.z, acc[i][3] + bv.w);
            *(float4*)&xz[(size_t)r * 1024 + col] = o;
        }
    } else if (bid < 386) {               // cz[n] = b_e + b_se@Wx_e
        int n = (bid - 384) * 512 + t;
        float acc = b_e[n];
        for (int k = 0; k < 256; k++) acc = fmaf(b_se[k], Wx_e[(size_t)k * 1024 + n], acc);
        cz[n] = acc;
    } else if (bid < 388) {               // hw[n] = cz[n] + init_b@Wh_e
        int n = (bid - 386) * 512 + t;
        float acc = b_e[n];
        for (int k = 0; k < 256; k++) {
            acc = fmaf(b_se[k], Wx_e[(size_t)k * 1024 + n], acc);
            acc = fmaf(init_b[k], Wh_e[(size_t)k * 1024 + n], acc);
        }
        hw[n] = acc;
    } else if (bid == 388) {              // ck
        if (t < 256) {
            float acc = b_sd[t];
            for (int k = 0; k < 256; k++) acc = fmaf(b_se[k], W_sd[(size_t)k * 256 + t], acc);
            ck[t] = acc;
        }
    } else {                              // init c0/h0/p0: 8 rows per block
        int r0 = (bid - 389) * 8 + (t >> 8) * 4;
        int col = t & 255;
        float ia = init_a[col], ib = init_b[col];
#pragma unroll
        for (int rr = 0; rr < 4; rr++) {
            int row = r0 + rr;
            if (row < R_) {
                c0[(size_t)row * 256 + col] = ia;
                h0[(size_t)row * 256 + col] = ib;
                if (col == 0) p0[row] = ((row % N_) == 0) ? 1.0f : 0.0f;
            }
        }
    }
}

// ============ templated GEMM: C = A@W (+bias)(-subQ), p-gated rows, MT x 128 tile ============
template<int MT>
__global__ __launch_bounds__(256) void gemm_t(const float* __restrict__ A,
        const float* __restrict__ W, const float* __restrict__ bias,
        const float* __restrict__ subQ, const float* __restrict__ pgate,
        float* __restrict__ C, int R, int NC) {
    __shared__ float As[MT][260];
    __shared__ int anyflag;
    int t = threadIdx.x;
    int n0 = blockIdx.x * 128;
    int r0 = blockIdx.y * MT;
    if (pgate) {                          // skip blocks whose rows all have p == 0
        if (t == 0) anyflag = 0;
        __syncthreads();
        if (t < MT && r0 + t < R && pgate[r0 + t] != 0.0f) anyflag = 1;
        __syncthreads();
        if (!anyflag) return;
    }
#pragma unroll
    for (int m = 0; m < MT / 4; m++) {
        int L = m * 256 + t;
        int r = L >> 6, c4 = (L & 63) * 4;
        int rr = r0 + r;
        float4 v = make_float4(0.f, 0.f, 0.f, 0.f);
        if (rr < R) v = *(const float4*)(A + (size_t)rr * 256 + c4);
        *(float4*)&As[r][c4] = v;
    }
    __syncthreads();
    constexpr int RT = MT / 8;
    int rg = t >> 5, cg = t & 31;
    float acc[RT][4] = {};
    const float* wp = W + n0 + 4 * cg;
#pragma unroll 2
    for (int kb = 0; kb < 64; kb++) {
        float4 w0 = *(const float4*)(wp + (size_t)(4 * kb + 0) * NC);
        float4 w1 = *(const float4*)(wp + (size_t)(4 * kb + 1) * NC);
        float4 w2 = *(const float4*)(wp + (size_t)(4 * kb + 2) * NC);
        float4 w3 = *(const float4*)(wp + (size_t)(4 * kb + 3) * NC);
#pragma unroll
        for (int i = 0; i < RT; i++) {
            float4 a = *(const float4*)&As[rg * RT + i][4 * kb];
            acc[i][0] = fmaf(a.x, w0.x, acc[i][0]);
            acc[i][1] = fmaf(a.x, w0.y, acc[i][1]);
            acc[i][2] = fmaf(a.x, w0.z, acc[i][2]);
            acc[i][3] = fmaf(a.x, w0.w, acc[i][3]);
            acc[i][0] = fmaf(a.y, w1.x, acc[i][0]);
            acc[i][1] = fmaf(a.y, w1.y, acc[i][1]);
            acc[i][2] = fmaf(a.y, w1.z, acc[i][2]);
            acc[i][3] = fmaf(a.y, w1.w, acc[i][3]);
            acc[i][0] = fmaf(a.z, w2.x, acc[i][0]);
            acc[i][1] = fmaf(a.z, w2.y, acc[i][1]);
            acc[i][2] = fmaf(a.z, w2.z, acc[i][2]);
            acc[i][3] = fmaf(a.z, w2.w, acc[i][3]);
            acc[i][0] = fmaf(a.w, w3.x, acc[i][0]);
            acc[i][1] = fmaf(a.w, w3.y, acc[i][1]);
            acc[i][2] = fmaf(a.w, w3.z, acc[i][2]);
            acc[i][3] = fmaf(a.w, w3.w, acc[i][3]);
        }
    }
    int col = n0 + 4 * cg;
    float4 bv = make_float4(0.f, 0.f, 0.f, 0.f);
    if (bias) bv = *(const float4*)&bias[col];
#pragma unroll
    for (int i = 0; i < RT; i++) {
        int r = r0 + rg * RT + i;
        if (r < R) {
            float4 o = make_float4(acc[i][0] + bv.x, acc[i][1] + bv.y,
                                   acc[i][2] + bv.z, acc[i][3] + bv.w);
            if (subQ) {
                float4 s4 = *(const float4*)(subQ + (size_t)r * NC + col);
                o.x -= s4.x; o.y -= s4.y; o.z -= s4.z; o.w -= s4.w;
            }
            *(float4*)&C[(size_t)r * NC + col] = o;
        }
    }
}

// ============ merged q/r GEMM: bx<8 -> q (and ve0 = hw - q); else r (+rT) ============
__global__ __launch_bounds__(256) void qr_kernel(const float* __restrict__ S,
        const float* __restrict__ Wx_e, const float* __restrict__ W_sd,
        const float* __restrict__ hw, float* __restrict__ q, float* __restrict__ ve0,
        float* __restrict__ r_, float* __restrict__ rT) {
    __shared__ float As[16][260];
    int t = threadIdx.x;
    int bx = blockIdx.x;
    int r0 = blockIdx.y * 16;
#pragma unroll
    for (int m = 0; m < 4; m++) {
        int L = m * 256 + t;
        int r = L >> 6, c4 = (L & 63) * 4;
        int rr = r0 + r;
        float4 v = make_float4(0.f, 0.f, 0.f, 0.f);
        if (rr < R_) v = *(const float4*)(S + (size_t)rr * 256 + c4);
        *(float4*)&As[r][c4] = v;
    }
    __syncthreads();
    bool isq = bx < 8;
    const float* W = isq ? Wx_e : W_sd;
    int NC = isq ? 1024 : 256;
    int n0 = (isq ? bx : bx - 8) * 128;
    int rg = t >> 5, cg = t & 31;
    float acc[2][4] = {};
    const float* wp = W + n0 + 4 * cg;
#pragma unroll 2
    for (int kb = 0; kb < 64; kb++) {
        float4 w0 = *(const float4*)(wp + (size_t)(4 * kb + 0) * NC);
        float4 w1 = *(const float4*)(wp + (size_t)(4 * kb + 1) * NC);
        float4 w2 = *(const float4*)(wp + (size_t)(4 * kb + 2) * NC);
        float4 w3 = *(const float4*)(wp + (size_t)(4 * kb + 3) * NC);
#pragma unroll
        for (int i = 0; i < 2; i++) {
            float4 a = *(const float4*)&As[rg * 2 + i][4 * kb];
            acc[i][0] = fmaf(a.x, w0.x, acc[i][0]);
            acc[i][1] = fmaf(a.x, w0.y, acc[i][1]);
            acc[i][2] = fmaf(a.x, w0.z, acc[i][2]);
            acc[i][3] = fmaf(a.x, w0.w, acc[i][3]);
            acc[i][0] = fmaf(a.y, w1.x, acc[i][0]);
            acc[i][1] = fmaf(a.y, w1.y, acc[i][1]);
            acc[i][2] = fmaf(a.y, w1.z, acc[i][2]);
            acc[i][3] = fmaf(a.y, w1.w, acc[i][3]);
            acc[i][0] = fmaf(a.z, w2.x, acc[i][0]);
            acc[i][1] = fmaf(a.z, w2.y, acc[i][1]);
            acc[i][2] = fmaf(a.z, w2.z, acc[i][2]);
            acc[i][3] = fmaf(a.z, w2.w, acc[i][3]);
            acc[i][0] = fmaf(a.w, w3.x, acc[i][0]);
            acc[i][1] = fmaf(a.w, w3.y, acc[i][1]);
            acc[i][2] = fmaf(a.w, w3.z, acc[i][2]);
            acc[i][3] = fmaf(a.w, w3.w, acc[i][3]);
        }
    }
    int col = n0 + 4 * cg;
#pragma unroll
    for (int i = 0; i < 2; i++) {
        int r = r0 + rg * 2 + i;
        if (r < R_) {
            float4 o = make_float4(acc[i][0], acc[i][1], acc[i][2], acc[i][3]);
            if (isq) {
                *(float4*)&q[(size_t)r * 1024 + col] = o;
                float4 hwv = *(const float4*)&hw[col];   // ve0 = hw - q (h0 rows identical)
                float4 v0 = make_float4(hwv.x - o.x, hwv.y - o.y, hwv.z - o.z, hwv.w - o.w);
                *(float4*)&ve0[(size_t)r * 1024 + col] = v0;
            } else {
                *(float4*)&r_[(size_t)r * 256 + col] = o;
                int b = r / N_, n = r - b * N_;
                rT[((size_t)b * 256 + col + 0) * 128 + n] = o.x;
                rT[((size_t)b * 256 + col + 1) * 128 + n] = o.y;
                rT[((size_t)b * 256 + col + 2) * 128 + n] = o.z;
                rT[((size_t)b * 256 + col + 3) * 128 + n] = o.w;
            }
        }
    }
}

// ============ LSTM steps 0+1 fused ============
__global__ __launch_bounds__(256) void lstm_first(const float* __restrict__ xz,
        const float* __restrict__ Wh, float* __restrict__ hbuf, float* __restrict__ cbuf) {
    __shared__ float Wh_s[256][64];
    __shared__ float h_s[32][260];
    __shared__ float zs[32][68];
    int t = threadIdx.x;
    int ct = blockIdx.x, st = blockIdx.y;
    int et0 = ct * 16, s0 = st * 32;
#pragma unroll
    for (int m = 0; m < 16; m++) {
        int L = m * 256 + t;
        int k = L >> 4, f = L & 15;
        int gg = f >> 2, qq = f & 3;
        *(float4*)&Wh_s[k][f * 4] = *(const float4*)&Wh[(size_t)k * 1024 + gg * 256 + et0 + qq * 4];
    }
    for (int seq = 0; seq < 32; seq++) {
        const float* z0 = xz + ((size_t)(s0 + seq) * T_) * 1024;
        float gi = z0[t], gg = z0[512 + t], go = z0[768 + t];
        float c0v = sigm(gi) * tanh_f(gg);
        h_s[seq][t] = sigm(go) * tanh_f(c0v);
    }
    float creg[2];
    {
        int sqA = t >> 4, e = et0 + (t & 15);
#pragma unroll
        for (int u = 0; u < 2; u++) {
            const float* z0 = xz + ((size_t)(s0 + sqA + u * 16) * T_) * 1024;
            creg[u] = sigm(z0[e]) * tanh_f(z0[512 + e]);
        }
    }
    __syncthreads();
    {
        int sp = (t >> 4) & 15, cq = t & 15;
        int g = cq >> 2, q4 = cq & 3;
        int gcol = g * 256 + et0 + q4 * 4;
        float4 a0 = *(const float4*)(xz + ((size_t)(s0 + sp) * T_ + 1) * 1024 + gcol);
        float4 a1 = *(const float4*)(xz + ((size_t)(s0 + sp + 16) * T_ + 1) * 1024 + gcol);
#pragma unroll 4
        for (int k = 0; k < 256; k++) {
            float4 w4 = *(const float4*)&Wh_s[k][cq * 4];
            float hA = h_s[sp][k];
            float hB = h_s[sp + 16][k];
            a0.x = fmaf(hA, w4.x, a0.x); a0.y = fmaf(hA, w4.y, a0.y);
            a0.z = fmaf(hA, w4.z, a0.z); a0.w = fmaf(hA, w4.w, a0.w);
            a1.x = fmaf(hB, w4.x, a1.x); a1.y = fmaf(hB, w4.y, a1.y);
            a1.z = fmaf(hB, w4.z, a1.z); a1.w = fmaf(hB, w4.w, a1.w);
        }
        *(float4*)&zs[sp][cq * 4] = a0;
        *(float4*)&zs[sp + 16][cq * 4] = a1;
    }
    __syncthreads();
    {
        int sqA = t >> 4, e = t & 15;
#pragma unroll
        for (int u = 0; u < 2; u++) {
            int seq = sqA + u * 16;
            float gi = zs[seq][e], gf = zs[seq][16 + e], gg = zs[seq][32 + e], go = zs[seq][48 + e];
            float cn = sigm(gf) * creg[u] + sigm(gi) * tanh_f(gg);
            size_t gidx = (size_t)(s0 + seq) * H_ + et0 + e;
            cbuf[gidx] = cn;
            hbuf[gidx] = sigm(go) * tanh_f(cn);
        }
    }
}

// ============ LSTM one step (steps 2..7) ============
__global__ __launch_bounds__(256) void lstm_step(int step, const float* __restrict__ xz,
        const float* __restrict__ Wh, float* __restrict__ hbuf, float* __restrict__ cbuf) {
    __shared__ float Wh_s[256][64];
    __shared__ float h_s[32][260];
    __shared__ float zs[32][68];
    int t = threadIdx.x;
    int ct = blockIdx.x, st = blockIdx.y;
    int et0 = ct * 16, s0 = st * 32;
    int sp = t >> 4, cq = t & 15;
    int g = cq >> 2, q4 = cq & 3;
    int gcol = g * 256 + et0 + q4 * 4;
    float4 a0 = *(const float4*)(xz + ((size_t)(s0 + sp) * T_ + step) * 1024 + gcol);
    float4 a1 = *(const float4*)(xz + ((size_t)(s0 + sp + 16) * T_ + step) * 1024 + gcol);
#pragma unroll
    for (int m = 0; m < 16; m++) {
        int L = m * 256 + t;
        int k = L >> 4, f = L & 15;
        int gg = f >> 2, qq = f & 3;
        *(float4*)&Wh_s[k][f * 4] = *(const float4*)&Wh[(size_t)k * 1024 + gg * 256 + et0 + qq * 4];
    }
#pragma unroll
    for (int m = 0; m < 8; m++) {
        int L = m * 256 + t;
        int seq = L >> 6, c4 = (L & 63) * 4;
        *(float4*)&h_s[seq][c4] = *(const float4*)&hbuf[(size_t)(s0 + seq) * H_ + c4];
    }
    __syncthreads();
#pragma unroll 4
    for (int k = 0; k < 256; k++) {
        float4 w4 = *(const float4*)&Wh_s[k][cq * 4];
        float h0 = h_s[sp][k];
        float h1 = h_s[sp + 16][k];
        a0.x = fmaf(h0, w4.x, a0.x); a0.y = fmaf(h0, w4.y, a0.y);
        a0.z = fmaf(h0, w4.z, a0.z); a0.w = fmaf(h0, w4.w, a0.w);
        a1.x = fmaf(h1, w4.x, a1.x); a1.y = fmaf(h1, w4.y, a1.y);
        a1.z = fmaf(h1, w4.z, a1.z); a1.w = fmaf(h1, w4.w, a1.w);
    }
    *(float4*)&zs[sp][cq * 4] = a0;
    *(float4*)&zs[sp + 16][cq * 4] = a1;
    __syncthreads();
    int seqA = t >> 4, e = t & 15;
#pragma unroll
    for (int u = 0; u < 2; u++) {
        int seq = seqA + u * 16;
        float gi = zs[seq][e], gf = zs[seq][16 + e], gg = zs[seq][32 + e], go = zs[seq][48 + e];
        size_t gidx = (size_t)(s0 + seq) * H_ + et0 + e;
        float cnew = sigm(gf) * cbuf[gidx] + sigm(gi) * tanh_f(gg);
        cbuf[gidx] = cnew;
        hbuf[gidx] = sigm(go) * tanh_f(cnew);
    }
}

// ============ cumsum v2: stage whole batch in LDS, scan in-LDS ============
__global__ __launch_bounds__(1024) void cumsum_k(const float* __restrict__ stmt,
                                                 float* __restrict__ pref) {
    __shared__ float buf[96][256];       // 98.3 KB
    int b = blockIdx.x, t = threadIdx.x;
#pragma unroll
    for (int m = 0; m < 6; m++) {        // 6144 float4, coalesced, independent
        int L = m * 1024 + t;
        int r = L >> 6, c4 = (L & 63) * 4;
        *(float4*)&buf[r][c4] = *(const float4*)(stmt + ((size_t)b * NS_ + r) * 256 + c4);
    }
    __syncthreads();
    if (t < 256) {
        float run = 0.0f;
        pref[((size_t)b * N_) * H_ + t] = 0.0f;
        for (int n = 1; n < N_; n++) {
            run += buf[n - 1][t];
            pref[((size_t)b * N_ + n) * H_ + t] = run;
        }
    }
}

// ============ ONCE: logits + masked softmax (layer-invariant) ============
__global__ void softmax_once(const float* __restrict__ r, const float* __restrict__ rT,
                             const float* __restrict__ ck, const float* __restrict__ Wd1,
                             const int* __restrict__ code_length,
                             float* __restrict__ spT_mid, float* __restrict__ spT0,
                             float* __restrict__ spT5) {
    __shared__ float ri[H_], ckl[H_], wd[H_];
    __shared__ float part[8][128];
    __shared__ float red[128];
    int t = threadIdx.x;             // 0..1023
    int j = t & 127, half = t >> 7;
    int bi = blockIdx.x;
    int b = bi / N_, i = bi % N_;
    if (t < H_) {
        ri[t] = r[(size_t)bi * H_ + t];
        ckl[t] = ck[t];
        wd[t] = Wd1[256 + t];
    }
    __syncthreads();
    int len = code_length[b] / T_;
    bool valid = (j < N_) && ((j > i && j <= len) || (j == len));
    float acc = 0.0f;
    if (valid) {
        const float* rTb = rT + (size_t)b * H_ * 128 + j;
        int h0 = half * 32;
#pragma unroll 4
        for (int hh = 0; hh < 32; hh++) {
            int h = h0 + hh;
            float v = rTb[(size_t)h * 128] - ri[h] + ckl[h];
            acc = fmaf(fmaxf(v, 0.0f), wd[h], acc);
        }
    }
    part[half][j] = acc;
    __syncthreads();
    float logit = -3.0e38f;
    if (t < 128) {
        if (valid)
            logit = part[0][j] + part[1][j] + part[2][j] + part[3][j]
                  + part[4][j] + part[5][j] + part[6][j] + part[7][j];
        red[j] = logit;
    }
    __syncthreads();
    for (int off = 64; off; off >>= 1) {
        if (t < off) red[t] = fmaxf(red[t], red[t + off]);
        __syncthreads();
    }
    float m = red[0];
    __syncthreads();
    float e = (t < 128 && valid) ? __builtin_amdgcn_exp2f(1.44269504f * (logit - m)) : 0.0f;
    if (t < 128) red[j] = e;
    __syncthreads();
    for (int off = 64; off; off >>= 1) {
        if (t < off) red[t] += red[t + off];
        __syncthreads();
    }
    float s = red[0];
    if (t < 128 && j < N_) {
        size_t o = ((size_t)b * N_ + j) * 128 + i;
        spT_mid[o] = e / s;
        spT0[o] = (j == 1) ? 1.0f : 0.0f;
        spT5[o] = (j == len) ? 1.0f : 0.0f;
    }
}

// ============ per-layer aggregate: gates = q[j] + ve[i]; 512 thr ============
__global__ __launch_bounds__(512) void aggregate(const float* __restrict__ q,
        const float* __restrict__ ve, const float* __restrict__ spT,
        const float* __restrict__ p, const float* __restrict__ cc,
        const float* __restrict__ hc, float* __restrict__ cn,
        float* __restrict__ hn, float* __restrict__ pn) {
    __shared__ float qj[1024];
    __shared__ float wcol[128];
    __shared__ float red[128];
    __shared__ int vlist[128];
    __shared__ int nv_s;
    __shared__ float parts[2][2][H_];
    int t = threadIdx.x;
    int bj = blockIdx.x;
    int b = bj / N_, j = bj - b * N_;
    if (t < 128) {
        float wv = (t < N_) ? spT[(size_t)bj * 128 + t] * p[b * N_ + t] : 0.f;
        wcol[t] = wv;
        red[t] = wv;
    }
    __syncthreads();
    if (t == 0) {
        int nv = 0;
        for (int i = 0; i < N_; i++)
            if (wcol[i] != 0.0f) vlist[nv++] = i;
        nv_s = nv;
    }
    __syncthreads();
    for (int off = 64; off; off >>= 1) {
        if (t < off) red[t] += red[t + off];
        __syncthreads();
    }
    float wsum = red[0];
    if (wsum == 0.0f) {
        if (t < 256) {
            cn[(size_t)bj * H_ + t] = 0.0f;
            hn[(size_t)bj * H_ + t] = 0.0f;
            if (t == 0) pn[bj] = 0.0f;
        }
        return;
    }
    qj[t] = q[(size_t)bj * 1024 + t];
    qj[512 + t] = q[(size_t)bj * 1024 + 512 + t];
    __syncthreads();
    int hh = t & 255, vs = t >> 8;
    int nv = nv_s;
    float ac = 0.f, ah = 0.f;
    for (int v = vs; v < nv; v += 2) {
        int i = vlist[v];
        float wv = wcol[i];
        size_t rowi = (size_t)b * N_ + i;
        if (j > i) {
            const float* vei = ve + rowi * 1024;
            float gi = qj[hh] + vei[hh];
            float gf = qj[256 + hh] + vei[256 + hh];
            float gg = qj[512 + hh] + vei[512 + hh];
            float go = qj[768 + hh] + vei[768 + hh];
            float c2 = cc[rowi * H_ + hh];
            float cp = sigm(gf) * c2 + sigm(gi) * tanh_f(gg);
            float hp = sigm(go) * tanh_f(cp);
            ac = fmaf(wv, cp, ac);
            ah = fmaf(wv, hp, ah);
        } else {
            ac = fmaf(wv, cc[rowi * H_ + hh], ac);
            ah = fmaf(wv, hc[rowi * H_ + hh], ah);
        }
    }
    parts[vs][0][hh] = ac;
    parts[vs][1][hh] = ah;
    __syncthreads();
    if (t < 256) {
        float inv = __builtin_amdgcn_rcpf(wsum + 1e-7f);
        cn[(size_t)bj * H_ + t] = (parts[0][0][t] + parts[1][0][t]) * inv;
        hn[(size_t)bj * H_ + t] = (parts[0][1][t] + parts[1][1][t]) * inv;
        if (t == 0) pn[bj] = wsum;
    }
}

// ---------------- host launcher ----------------

extern "C" void kernel_launch(void* const* d_in, const int* in_sizes, int n_in,
                              void* d_out, int out_size, void* d_ws, size_t ws_size,
                              hipStream_t stream) {
    const int*   code_statements = (const int*)d_in[0];
    const int*   code_length = (const int*)d_in[1];
    const float* embed = (const float*)d_in[2];
    const float* Wx_s = (const float*)d_in[3];
    const float* Wh_s = (const float*)d_in[4];
    const float* b_s  = (const float*)d_in[5];
    const float* W_se = (const float*)d_in[6];
    const float* b_se = (const float*)d_in[7];
    const float* Wx_e = (const float*)d_in[8];
    const float* Wh_e = (const float*)d_in[9];
    const float* b_e  = (const float*)d_in[10];
    const float* W_sd = (const float*)d_in[13];
    const float* b_sd = (const float*)d_in[14];
    const float* W_d1 = (const float*)d_in[15];
    // d_in[11] W_hk, d_in[12] b_hk, d_in[16] b_d1: softmax-invariant -> unused
    const float* init_a = (const float*)d_in[17];
    const float* init_b = (const float*)d_in[18];
    float* out = (float*)d_out;

    float* wsf = (float*)d_ws;
    size_t off = 0;
    auto alloc = [&](size_t n) { float* p = wsf + off; off += n; return p; };
    float* cz = alloc(1024);
    float* ck = alloc(256);
    float* hw = alloc(1024);             // init_b@Wh_e + cz
    float* xz = alloc((size_t)3072 * 1024);
    float* stmt = alloc(384 * 256);      // LSTM h buffer
    float* cls = alloc(384 * 256);       // LSTM cell state
    float* pref = alloc(R_ * 256);
    float* s_   = alloc(R_ * 256);       // pref @ W_se
    float* q  = alloc(R_ * 1024);
    float* r_ = alloc(R_ * 256);
    float* rT = alloc(4 * 256 * 128);
    float* ve = alloc(R_ * 1024);        // h@Wh_e + cz - q
    float* spT_mid = alloc(R_ * 128);
    float* spT0    = alloc(R_ * 128);
    float* spT5    = alloc(R_ * 128);
    float* p0 = alloc(R_);
    float* p1 = alloc(R_);
    float* c0 = alloc(R_ * 256);
    float* c1 = alloc(R_ * 256);
    float* h0 = alloc(R_ * 256);
    float* h1 = alloc(R_ * 256);

    // one prologue launch: xz (64x128 tiles) + cz/ck/hw + state init
    prologue<<<dim3(438), 512, 0, stream>>>(code_statements, embed, Wx_s, b_s,
                                            b_se, Wx_e, b_e, W_sd, b_sd, Wh_e,
                                            init_a, init_b, xz, cz, ck, hw, c0, h0, p0);
    // LSTM: steps 0+1 fused, then 2..7
    lstm_first<<<dim3(16, 12), 256, 0, stream>>>(xz, Wh_s, stmt, cls);
    for (int step = 2; step < T_; step++)
        lstm_step<<<dim3(16, 12), 256, 0, stream>>>(step, xz, Wh_s, stmt, cls);
    cumsum_k<<<dim3(4), 1024, 0, stream>>>(stmt, pref);
    gemm_t<16><<<dim3(2, 25), 256, 0, stream>>>(pref, W_se, nullptr, nullptr, nullptr,
                                                s_, R_, 256);
    qr_kernel<<<dim3(10, 25), 256, 0, stream>>>(s_, Wx_e, W_sd, hw, q, ve, r_, rT);
    softmax_once<<<dim3(R_), 1024, 0, stream>>>(r_, rT, ck, W_d1, code_length,
                                                spT_mid, spT0, spT5);

    // execution layers (ve0 already produced by qr_kernel)
    for (int layer = 0; layer < NL_; layer++) {
        bool odd = (layer & 1);
        float* pc = odd ? p1 : p0;
        float* pn = odd ? p0 : p1;
        float* cc = odd ? c1 : c0;
        float* cn = odd ? c0 : c1;
        float* hc = odd ? h1 : h0;
        float* hn = odd ? h0 : h1;
        if (layer == NL_ - 1) hn = out;  // final h straight to d_out
        const float* spT = (layer == 0) ? spT0 : (layer == NL_ - 1) ? spT5 : spT_mid;
        aggregate<<<dim3(R_), 512, 0, stream>>>(q, ve, spT, pc, cc, hc, cn, hn, pn);
        if (layer < NL_ - 1)
            gemm_t<16><<<dim3(8, 25), 256, 0, stream>>>(hn, Wh_e, cz, q, pn,
                                                        ve, R_, 1024);
    }
}